// Round 1
// baseline (1095.967 us; speedup 1.0000x reference)
//
#include <hip/hip_runtime.h>

#define M_NODES 50000
#define KDIM    256
#define NDIM    96
#define NDIM4   24      // NDIM/4
#define NEDGE   800000

// -------- Kernel 1: hw = (h @ W) * norm --------------------------------
// Block: 256 threads. Each block computes 128 rows x 96 channels.
// W (256x96 f32 = 96 KB) staged once in LDS as float4-over-channels.
// h staged in 128x64 chunks (34 KB w/ pad). Per-thread tile: 4 rows x 12 ch.
__global__ __launch_bounds__(256) void gemm_norm_kernel(
    const float* __restrict__ h, const float* __restrict__ norm,
    const float* __restrict__ w, float* __restrict__ hw)
{
    __shared__ float4 wt4[KDIM][NDIM4];   // [256][24] = 96 KB
    __shared__ float4 h4[128][17];        // 16 float4 per row + 1 pad = 34 KB

    const int tid = threadIdx.x;
    const int rg  = tid >> 3;   // 0..31 row-group (rows rg, rg+32, rg+64, rg+96)
    const int cg  = tid & 7;    // 0..7  channel-group (channels cg*12 .. +11)
    const int blockRow = blockIdx.x * 128;

    // Stage W: wt4[k][c4] = W[k][4*c4 .. 4*c4+3]
    for (int i = tid; i < KDIM * NDIM4; i += 256) {
        int k  = i / NDIM4;
        int c4 = i - k * NDIM4;
        wt4[k][c4] = *reinterpret_cast<const float4*>(w + k * NDIM + c4 * 4);
    }

    float4 acc[4][3];
#pragma unroll
    for (int r = 0; r < 4; ++r)
#pragma unroll
        for (int c = 0; c < 3; ++c)
            acc[r][c] = make_float4(0.f, 0.f, 0.f, 0.f);

    for (int kc = 0; kc < 4; ++kc) {
        const int k0 = kc * 64;
        __syncthreads();   // also covers wt4 staging on kc==0
        // stage h chunk: 128 rows x 64 k (16 float4/row)
#pragma unroll
        for (int it = 0; it < 8; ++it) {
            int idx = tid + it * 256;
            int r   = idx >> 4;
            int kk  = idx & 15;
            int row = blockRow + r;
            float4 v = make_float4(0.f, 0.f, 0.f, 0.f);
            if (row < M_NODES)
                v = *reinterpret_cast<const float4*>(h + row * KDIM + k0 + kk * 4);
            h4[r][kk] = v;
        }
        __syncthreads();

#pragma unroll
        for (int kk = 0; kk < 16; ++kk) {
            float4 hv[4];
#pragma unroll
            for (int r = 0; r < 4; ++r) hv[r] = h4[rg + 32 * r][kk];
#pragma unroll
            for (int j = 0; j < 4; ++j) {
                float4 wv[3];
#pragma unroll
                for (int c = 0; c < 3; ++c) wv[c] = wt4[k0 + kk * 4 + j][cg * 3 + c];
#pragma unroll
                for (int r = 0; r < 4; ++r) {
                    float hs = (j == 0) ? hv[r].x : (j == 1) ? hv[r].y
                             : (j == 2) ? hv[r].z : hv[r].w;
#pragma unroll
                    for (int c = 0; c < 3; ++c) {
                        acc[r][c].x += hs * wv[c].x;
                        acc[r][c].y += hs * wv[c].y;
                        acc[r][c].z += hs * wv[c].z;
                        acc[r][c].w += hs * wv[c].w;
                    }
                }
            }
        }
    }

    // epilogue: multiply by norm[row], store
#pragma unroll
    for (int r = 0; r < 4; ++r) {
        int row = blockRow + rg + 32 * r;
        if (row < M_NODES) {
            float nv = norm[row];
#pragma unroll
            for (int c = 0; c < 3; ++c) {
                float4 v = acc[r][c];
                v.x *= nv; v.y *= nv; v.z *= nv; v.w *= nv;
                *reinterpret_cast<float4*>(hw + row * NDIM + (cg * 3 + c) * 4) = v;
            }
        }
    }
}

// -------- Kernel 2: scatter-add messages -------------------------------
// One thread per (edge, 4-channel group): 800000 * 24 units.
__global__ __launch_bounds__(256) void scatter_kernel(
    const float* __restrict__ hw, const int* __restrict__ src,
    const int* __restrict__ dst, float* __restrict__ agg)
{
    int idx = blockIdx.x * 256 + threadIdx.x;
    if (idx >= NEDGE * NDIM4) return;
    int e = idx / NDIM4;
    int g = idx - e * NDIM4;
    int s = src[e];
    int d = dst[e];
    float4 v = *reinterpret_cast<const float4*>(hw + s * NDIM + g * 4);
    float* ap = agg + d * NDIM + g * 4;
    atomicAdd(ap + 0, v.x);
    atomicAdd(ap + 1, v.y);
    atomicAdd(ap + 2, v.z);
    atomicAdd(ap + 3, v.w);
}

// -------- Kernel 3: out = relu(agg * norm) -----------------------------
__global__ __launch_bounds__(256) void finalize_kernel(
    const float* __restrict__ agg, const float* __restrict__ norm,
    float* __restrict__ out)
{
    int idx = blockIdx.x * 256 + threadIdx.x;   // float4 index
    if (idx >= M_NODES * NDIM4) return;
    int row = idx / NDIM4;
    float nv = norm[row];
    float4 v = reinterpret_cast<const float4*>(agg)[idx];
    v.x = fmaxf(v.x * nv, 0.f);
    v.y = fmaxf(v.y * nv, 0.f);
    v.z = fmaxf(v.z * nv, 0.f);
    v.w = fmaxf(v.w * nv, 0.f);
    reinterpret_cast<float4*>(out)[idx] = v;
}

extern "C" void kernel_launch(void* const* d_in, const int* in_sizes, int n_in,
                              void* d_out, int out_size, void* d_ws, size_t ws_size,
                              hipStream_t stream)
{
    const float* h    = (const float*)d_in[0];
    const float* norm = (const float*)d_in[1];
    const float* w    = (const float*)d_in[2];
    const int*   src  = (const int*)d_in[3];
    const int*   dst  = (const int*)d_in[4];
    float* out = (float*)d_out;

    float* hw  = (float*)d_ws;                    // 50000*96 f32 = 19.2 MB
    float* agg = hw + (size_t)M_NODES * NDIM;     // another 19.2 MB

    hipMemsetAsync(agg, 0, (size_t)M_NODES * NDIM * sizeof(float), stream);

    gemm_norm_kernel<<<(M_NODES + 127) / 128, 256, 0, stream>>>(h, norm, w, hw);

    int scatter_units = NEDGE * NDIM4;
    scatter_kernel<<<(scatter_units + 255) / 256, 256, 0, stream>>>(hw, src, dst, agg);

    int fin_units = M_NODES * NDIM4;
    finalize_kernel<<<(fin_units + 255) / 256, 256, 0, stream>>>(agg, norm, out);
}

// Round 2
// 311.279 us; speedup vs baseline: 3.5209x; 3.5209x over previous
//
#include <hip/hip_runtime.h>

#define M_NODES 50000
#define KDIM    256
#define NDIM    96
#define NDIM4   24      // NDIM/4
#define NEDGE   800000

// -------- Kernel 1: hw = (h @ W) * norm --------------------------------
// Block: 256 threads. Each block computes 128 rows x 96 channels.
// W (256x96 f32 = 96 KB) staged once in LDS as float4-over-channels.
// h staged in 128x64 chunks (34 KB w/ pad). Per-thread tile: 4 rows x 12 ch.
__global__ __launch_bounds__(256) void gemm_norm_kernel(
    const float* __restrict__ h, const float* __restrict__ norm,
    const float* __restrict__ w, float* __restrict__ hw)
{
    __shared__ float4 wt4[KDIM][NDIM4];   // [256][24] = 96 KB
    __shared__ float4 h4[128][17];        // 16 float4 per row + 1 pad = 34 KB

    const int tid = threadIdx.x;
    const int rg  = tid >> 3;   // 0..31 row-group (rows rg, rg+32, rg+64, rg+96)
    const int cg  = tid & 7;    // 0..7  channel-group (channels cg*12 .. +11)
    const int blockRow = blockIdx.x * 128;

    // Stage W: wt4[k][c4] = W[k][4*c4 .. 4*c4+3]
    for (int i = tid; i < KDIM * NDIM4; i += 256) {
        int k  = i / NDIM4;
        int c4 = i - k * NDIM4;
        wt4[k][c4] = *reinterpret_cast<const float4*>(w + k * NDIM + c4 * 4);
    }

    float4 acc[4][3];
#pragma unroll
    for (int r = 0; r < 4; ++r)
#pragma unroll
        for (int c = 0; c < 3; ++c)
            acc[r][c] = make_float4(0.f, 0.f, 0.f, 0.f);

    for (int kc = 0; kc < 4; ++kc) {
        const int k0 = kc * 64;
        __syncthreads();   // also covers wt4 staging on kc==0
        // stage h chunk: 128 rows x 64 k (16 float4/row)
#pragma unroll
        for (int it = 0; it < 8; ++it) {
            int idx = tid + it * 256;
            int r   = idx >> 4;
            int kk  = idx & 15;
            int row = blockRow + r;
            float4 v = make_float4(0.f, 0.f, 0.f, 0.f);
            if (row < M_NODES)
                v = *reinterpret_cast<const float4*>(h + row * KDIM + k0 + kk * 4);
            h4[r][kk] = v;
        }
        __syncthreads();

#pragma unroll
        for (int kk = 0; kk < 16; ++kk) {
            float4 hv[4];
#pragma unroll
            for (int r = 0; r < 4; ++r) hv[r] = h4[rg + 32 * r][kk];
#pragma unroll
            for (int j = 0; j < 4; ++j) {
                float4 wv[3];
#pragma unroll
                for (int c = 0; c < 3; ++c) wv[c] = wt4[k0 + kk * 4 + j][cg * 3 + c];
#pragma unroll
                for (int r = 0; r < 4; ++r) {
                    float hs = (j == 0) ? hv[r].x : (j == 1) ? hv[r].y
                             : (j == 2) ? hv[r].z : hv[r].w;
#pragma unroll
                    for (int c = 0; c < 3; ++c) {
                        acc[r][c].x += hs * wv[c].x;
                        acc[r][c].y += hs * wv[c].y;
                        acc[r][c].z += hs * wv[c].z;
                        acc[r][c].w += hs * wv[c].w;
                    }
                }
            }
        }
    }

    // epilogue: multiply by norm[row], store
#pragma unroll
    for (int r = 0; r < 4; ++r) {
        int row = blockRow + rg + 32 * r;
        if (row < M_NODES) {
            float nv = norm[row];
#pragma unroll
            for (int c = 0; c < 3; ++c) {
                float4 v = acc[r][c];
                v.x *= nv; v.y *= nv; v.z *= nv; v.w *= nv;
                *reinterpret_cast<float4*>(hw + row * NDIM + (cg * 3 + c) * 4) = v;
            }
        }
    }
}

// -------- Kernel 2a: histogram of dst ----------------------------------
__global__ __launch_bounds__(256) void hist_kernel(
    const int* __restrict__ dst, int* __restrict__ cnt)
{
    int e = blockIdx.x * 256 + threadIdx.x;
    if (e < NEDGE) atomicAdd(&cnt[dst[e]], 1);
}

// -------- Kernel 2b: exclusive prefix sum over cnt (single block) ------
#define SCAN_T 1024
#define CHUNK  49   // ceil(50000/1024)
__global__ __launch_bounds__(SCAN_T) void scan_kernel(
    const int* __restrict__ cnt, int* __restrict__ off)
{
    __shared__ int sums[SCAN_T];
    const int t = threadIdx.x;
    const int base = t * CHUNK;

    int s = 0;
    for (int j = 0; j < CHUNK; ++j) {
        int i = base + j;
        if (i < M_NODES) s += cnt[i];
    }
    sums[t] = s;
    __syncthreads();
    for (int st = 1; st < SCAN_T; st <<= 1) {
        int v = (t >= st) ? sums[t - st] : 0;
        __syncthreads();
        sums[t] += v;
        __syncthreads();
    }
    int run = sums[t] - s;   // exclusive prefix of this thread's chunk
    for (int j = 0; j < CHUNK; ++j) {
        int i = base + j;
        if (i < M_NODES) { off[i] = run; run += cnt[i]; }
    }
    if (t == SCAN_T - 1) off[M_NODES] = sums[SCAN_T - 1];
}

// -------- Kernel 2c: bucket src ids by dst -----------------------------
__global__ __launch_bounds__(256) void build_kernel(
    const int* __restrict__ src, const int* __restrict__ dst,
    const int* __restrict__ off, int* __restrict__ cur,
    int* __restrict__ edge_src)
{
    int e = blockIdx.x * 256 + threadIdx.x;
    if (e >= NEDGE) return;
    int d = dst[e];
    int pos = atomicAdd(&cur[d], 1);
    edge_src[off[d] + pos] = src[e];
}

// -------- Kernel 3: gather-side segment sum + relu(agg*norm) -----------
// 24 consecutive threads = the 24 float4 channels of one dst node.
// 192 threads/block = 8 nodes/block; edge rows of hw read as contiguous 384B.
__global__ __launch_bounds__(192) void aggregate_kernel(
    const float* __restrict__ hw, const int* __restrict__ off,
    const int* __restrict__ edge_src, const float* __restrict__ norm,
    float* __restrict__ out)
{
    const int tid = threadIdx.x;
    const int n   = blockIdx.x * 8 + tid / 24;
    const int c4  = tid % 24;
    if (n >= M_NODES) return;

    const int e0 = off[n];
    const int e1 = off[n + 1];
    float4 acc = make_float4(0.f, 0.f, 0.f, 0.f);
    for (int e = e0; e < e1; ++e) {
        int s = edge_src[e];
        float4 v = *reinterpret_cast<const float4*>(hw + (size_t)s * NDIM + c4 * 4);
        acc.x += v.x; acc.y += v.y; acc.z += v.z; acc.w += v.w;
    }
    float nv = norm[n];
    float4 r;
    r.x = fmaxf(acc.x * nv, 0.f);
    r.y = fmaxf(acc.y * nv, 0.f);
    r.z = fmaxf(acc.z * nv, 0.f);
    r.w = fmaxf(acc.w * nv, 0.f);
    *reinterpret_cast<float4*>(out + (size_t)n * NDIM + c4 * 4) = r;
}

extern "C" void kernel_launch(void* const* d_in, const int* in_sizes, int n_in,
                              void* d_out, int out_size, void* d_ws, size_t ws_size,
                              hipStream_t stream)
{
    const float* h    = (const float*)d_in[0];
    const float* norm = (const float*)d_in[1];
    const float* w    = (const float*)d_in[2];
    const int*   src  = (const int*)d_in[3];
    const int*   dst  = (const int*)d_in[4];
    float* out = (float*)d_out;

    // workspace layout
    float* hw       = (float*)d_ws;                 // 4,800,000 f32 (19.2 MB)
    int*   cnt      = (int*)(hw + 4800000);         // 50000
    int*   off      = cnt + 50000;                  // 50001 (+3 pad)
    int*   cur      = off + 50004;                  // 50000
    int*   edge_src = cur + 50000;                  // 800000

    hipMemsetAsync(cnt, 0, 50000 * sizeof(int), stream);
    hipMemsetAsync(cur, 0, 50000 * sizeof(int), stream);

    hist_kernel<<<(NEDGE + 255) / 256, 256, 0, stream>>>(dst, cnt);
    scan_kernel<<<1, SCAN_T, 0, stream>>>(cnt, off);
    build_kernel<<<(NEDGE + 255) / 256, 256, 0, stream>>>(src, dst, off, cur, edge_src);

    gemm_norm_kernel<<<(M_NODES + 127) / 128, 256, 0, stream>>>(h, norm, w, hw);

    aggregate_kernel<<<(M_NODES + 7) / 8, 192, 0, stream>>>(hw, off, edge_src, norm, out);
}

// Round 3
// 233.886 us; speedup vs baseline: 4.6859x; 1.3309x over previous
//
#include <hip/hip_runtime.h>

#define M_NODES 50000
#define KDIM    256
#define NDIM    96
#define NEDGE   800000
#define NB_SCAN 196   // ceil(50000/256)

// -------- Kernel 1: hw = (h @ W) * norm --------------------------------
// 128 threads/block, 32 rows/block, 2 rows x 12 channels per thread.
// No LDS: W served by L1/L2 (8-way intra-wave broadcast), h read once.
__global__ __launch_bounds__(128) void gemm_norm_kernel(
    const float* __restrict__ h, const float* __restrict__ norm,
    const float* __restrict__ w, float* __restrict__ hw)
{
    const int tid = threadIdx.x;
    const int rg  = tid >> 3;            // 0..15
    const int cg  = tid & 7;             // 0..7 -> channels cg*12 .. +11
    const int row0 = blockIdx.x * 32 + rg;
    const int row1 = row0 + 16;
    // clamp for safe loads; predicate stores
    const int r0c = row0 < M_NODES ? row0 : M_NODES - 1;
    const int r1c = row1 < M_NODES ? row1 : M_NODES - 1;

    const float* __restrict__ hr0 = h + (size_t)r0c * KDIM;
    const float* __restrict__ hr1 = h + (size_t)r1c * KDIM;
    const float* __restrict__ wc  = w + cg * 12;

    float4 acc[2][3];
#pragma unroll
    for (int r = 0; r < 2; ++r)
#pragma unroll
        for (int c = 0; c < 3; ++c)
            acc[r][c] = make_float4(0.f, 0.f, 0.f, 0.f);

#pragma unroll 4
    for (int k = 0; k < KDIM; k += 4) {
        float4 ha = *reinterpret_cast<const float4*>(hr0 + k);
        float4 hb = *reinterpret_cast<const float4*>(hr1 + k);
#pragma unroll
        for (int j = 0; j < 4; ++j) {
            const float* wr = wc + (size_t)(k + j) * NDIM;
            float4 w0 = *reinterpret_cast<const float4*>(wr + 0);
            float4 w1 = *reinterpret_cast<const float4*>(wr + 4);
            float4 w2 = *reinterpret_cast<const float4*>(wr + 8);
            float a = (j == 0) ? ha.x : (j == 1) ? ha.y : (j == 2) ? ha.z : ha.w;
            float b = (j == 0) ? hb.x : (j == 1) ? hb.y : (j == 2) ? hb.z : hb.w;
            acc[0][0].x += a * w0.x; acc[0][0].y += a * w0.y;
            acc[0][0].z += a * w0.z; acc[0][0].w += a * w0.w;
            acc[0][1].x += a * w1.x; acc[0][1].y += a * w1.y;
            acc[0][1].z += a * w1.z; acc[0][1].w += a * w1.w;
            acc[0][2].x += a * w2.x; acc[0][2].y += a * w2.y;
            acc[0][2].z += a * w2.z; acc[0][2].w += a * w2.w;
            acc[1][0].x += b * w0.x; acc[1][0].y += b * w0.y;
            acc[1][0].z += b * w0.z; acc[1][0].w += b * w0.w;
            acc[1][1].x += b * w1.x; acc[1][1].y += b * w1.y;
            acc[1][1].z += b * w1.z; acc[1][1].w += b * w1.w;
            acc[1][2].x += b * w2.x; acc[1][2].y += b * w2.y;
            acc[1][2].z += b * w2.z; acc[1][2].w += b * w2.w;
        }
    }

    if (row0 < M_NODES) {
        float nv = norm[row0];
#pragma unroll
        for (int c = 0; c < 3; ++c) {
            float4 v = acc[0][c];
            v.x *= nv; v.y *= nv; v.z *= nv; v.w *= nv;
            *reinterpret_cast<float4*>(hw + (size_t)row0 * NDIM + cg * 12 + c * 4) = v;
        }
    }
    if (row1 < M_NODES) {
        float nv = norm[row1];
#pragma unroll
        for (int c = 0; c < 3; ++c) {
            float4 v = acc[1][c];
            v.x *= nv; v.y *= nv; v.z *= nv; v.w *= nv;
            *reinterpret_cast<float4*>(hw + (size_t)row1 * NDIM + cg * 12 + c * 4) = v;
        }
    }
}

// -------- Kernel 2a: histogram of dst ----------------------------------
__global__ __launch_bounds__(256) void hist_kernel(
    const int* __restrict__ dst, int* __restrict__ cnt)
{
    int e = blockIdx.x * 256 + threadIdx.x;
    if (e < NEDGE) atomicAdd(&cnt[dst[e]], 1);
}

// -------- Kernel 2b: hierarchical exclusive scan -----------------------
__global__ __launch_bounds__(256) void scan1_kernel(
    const int* __restrict__ cnt, int* __restrict__ off, int* __restrict__ bsum)
{
    __shared__ int sh[256];
    const int t = threadIdx.x;
    const int i = blockIdx.x * 256 + t;
    int v = (i < M_NODES) ? cnt[i] : 0;
    sh[t] = v;
    __syncthreads();
    for (int st = 1; st < 256; st <<= 1) {
        int o = (t >= st) ? sh[t - st] : 0;
        __syncthreads();
        sh[t] += o;
        __syncthreads();
    }
    if (i < M_NODES) off[i] = sh[t] - v;   // exclusive (local)
    if (t == 255) bsum[blockIdx.x] = sh[t];
}

__global__ __launch_bounds__(256) void scan2_kernel(
    const int* __restrict__ bsum, int* __restrict__ bbase, int* __restrict__ off)
{
    __shared__ int sh[256];
    const int t = threadIdx.x;
    int v = (t < NB_SCAN) ? bsum[t] : 0;
    sh[t] = v;
    __syncthreads();
    for (int st = 1; st < 256; st <<= 1) {
        int o = (t >= st) ? sh[t - st] : 0;
        __syncthreads();
        sh[t] += o;
        __syncthreads();
    }
    if (t < NB_SCAN) bbase[t] = sh[t] - v;  // exclusive
    if (t == NB_SCAN - 1) off[M_NODES] = sh[t];
}

__global__ __launch_bounds__(256) void addbase_kernel(
    int* __restrict__ off, const int* __restrict__ bbase)
{
    int i = blockIdx.x * 256 + threadIdx.x;
    if (i < M_NODES) off[i] += bbase[i >> 8];
}

// -------- Kernel 2c: bucket src ids by dst -----------------------------
__global__ __launch_bounds__(256) void build_kernel(
    const int* __restrict__ src, const int* __restrict__ dst,
    const int* __restrict__ off, int* __restrict__ cur,
    int* __restrict__ edge_src)
{
    int e = blockIdx.x * 256 + threadIdx.x;
    if (e >= NEDGE) return;
    int d = dst[e];
    int pos = atomicAdd(&cur[d], 1);
    edge_src[off[d] + pos] = src[e];
}

// -------- Kernel 3: gather-side segment sum + relu(agg*norm) -----------
// 24 consecutive threads = 24 float4 channels of one dst node; 8 nodes/block.
// Edge loop unrolled x4 with 2 accumulators for memory-level parallelism.
__global__ __launch_bounds__(192) void aggregate_kernel(
    const float* __restrict__ hw, const int* __restrict__ off,
    const int* __restrict__ edge_src, const float* __restrict__ norm,
    float* __restrict__ out)
{
    const int tid = threadIdx.x;
    const int n   = blockIdx.x * 8 + tid / 24;
    const int c4  = tid % 24;
    if (n >= M_NODES) return;

    const int e0 = off[n];
    const int e1 = off[n + 1];
    float4 a0 = make_float4(0.f, 0.f, 0.f, 0.f);
    float4 a1 = make_float4(0.f, 0.f, 0.f, 0.f);

    int e = e0;
    for (; e + 4 <= e1; e += 4) {
        int s0 = edge_src[e + 0];
        int s1 = edge_src[e + 1];
        int s2 = edge_src[e + 2];
        int s3 = edge_src[e + 3];
        float4 v0 = *reinterpret_cast<const float4*>(hw + (size_t)s0 * NDIM + c4 * 4);
        float4 v1 = *reinterpret_cast<const float4*>(hw + (size_t)s1 * NDIM + c4 * 4);
        float4 v2 = *reinterpret_cast<const float4*>(hw + (size_t)s2 * NDIM + c4 * 4);
        float4 v3 = *reinterpret_cast<const float4*>(hw + (size_t)s3 * NDIM + c4 * 4);
        a0.x += v0.x; a0.y += v0.y; a0.z += v0.z; a0.w += v0.w;
        a1.x += v1.x; a1.y += v1.y; a1.z += v1.z; a1.w += v1.w;
        a0.x += v2.x; a0.y += v2.y; a0.z += v2.z; a0.w += v2.w;
        a1.x += v3.x; a1.y += v3.y; a1.z += v3.z; a1.w += v3.w;
    }
    for (; e < e1; ++e) {
        int s = edge_src[e];
        float4 v = *reinterpret_cast<const float4*>(hw + (size_t)s * NDIM + c4 * 4);
        a0.x += v.x; a0.y += v.y; a0.z += v.z; a0.w += v.w;
    }

    float nv = norm[n];
    float4 r;
    r.x = fmaxf((a0.x + a1.x) * nv, 0.f);
    r.y = fmaxf((a0.y + a1.y) * nv, 0.f);
    r.z = fmaxf((a0.z + a1.z) * nv, 0.f);
    r.w = fmaxf((a0.w + a1.w) * nv, 0.f);
    *reinterpret_cast<float4*>(out + (size_t)n * NDIM + c4 * 4) = r;
}

extern "C" void kernel_launch(void* const* d_in, const int* in_sizes, int n_in,
                              void* d_out, int out_size, void* d_ws, size_t ws_size,
                              hipStream_t stream)
{
    const float* h    = (const float*)d_in[0];
    const float* norm = (const float*)d_in[1];
    const float* w    = (const float*)d_in[2];
    const int*   src  = (const int*)d_in[3];
    const int*   dst  = (const int*)d_in[4];
    float* out = (float*)d_out;

    // workspace layout
    float* hw       = (float*)d_ws;              // 4,800,000 f32 = 19.2 MB
    int*   cnt      = (int*)(hw + 4800000);      // 50000
    int*   off      = cnt + 50000;               // 50001 (+3 pad)
    int*   cur      = off + 50004;               // 50000
    int*   bsum     = cur + 50000;               // 256
    int*   bbase    = bsum + 256;                // 256
    int*   edge_src = bbase + 256;               // 800000

    hipMemsetAsync(cnt, 0, 50000 * sizeof(int), stream);
    hipMemsetAsync(cur, 0, 50000 * sizeof(int), stream);

    hist_kernel<<<(NEDGE + 255) / 256, 256, 0, stream>>>(dst, cnt);
    scan1_kernel<<<NB_SCAN, 256, 0, stream>>>(cnt, off, bsum);
    scan2_kernel<<<1, 256, 0, stream>>>(bsum, bbase, off);
    addbase_kernel<<<NB_SCAN, 256, 0, stream>>>(off, bbase);
    build_kernel<<<(NEDGE + 255) / 256, 256, 0, stream>>>(src, dst, off, cur, edge_src);

    gemm_norm_kernel<<<(M_NODES + 31) / 32, 128, 0, stream>>>(h, norm, w, hw);

    aggregate_kernel<<<(M_NODES + 7) / 8, 192, 0, stream>>>(hw, off, edge_src, norm, out);
}

// Round 4
// 215.476 us; speedup vs baseline: 5.0863x; 1.0854x over previous
//
#include <hip/hip_runtime.h>

#define M_NODES 50000
#define KDIM    256
#define NDIM    96
#define NEDGE   800000
#define NB_SCAN 196   // ceil(50000/256)

// round-to-nearest-even f32 -> bf16 pair packed in u32 (lo = first)
__device__ inline unsigned pack2bf(float x, float y) {
    unsigned ux = __float_as_uint(x), uy = __float_as_uint(y);
    ux = (ux + 0x7fffu + ((ux >> 16) & 1u)) >> 16;
    uy = (uy + 0x7fffu + ((uy >> 16) & 1u)) >> 16;
    return ux | (uy << 16);
}

// -------- Kernel 1: hw_bf = bf16((h @ W) * norm) -----------------------
// 128 threads/block, 32 rows/block, 2 rows x 12 ch per thread.
// Register double-buffered: prefetch next 8-k slab of W+h during FMAs.
#define LOAD_SLOT(W_, ha_, hb_, kb)                                          \
    {                                                                        \
        _Pragma("unroll") for (int j = 0; j < 4; ++j)                        \
            _Pragma("unroll") for (int c = 0; c < 3; ++c)                    \
                W_[j * 3 + c] = *reinterpret_cast<const float4*>(            \
                    wp + (size_t)((kb) + j) * NDIM + c * 4);                 \
        ha_ = *reinterpret_cast<const float4*>(hr0 + (kb));                  \
        hb_ = *reinterpret_cast<const float4*>(hr1 + (kb));                  \
    }

#define FMA_SLOT(W_, ha_, hb_)                                               \
    {                                                                        \
        _Pragma("unroll") for (int j = 0; j < 4; ++j) {                      \
            float a = (j == 0) ? ha_.x : (j == 1) ? ha_.y                    \
                    : (j == 2) ? ha_.z : ha_.w;                              \
            float b = (j == 0) ? hb_.x : (j == 1) ? hb_.y                    \
                    : (j == 2) ? hb_.z : hb_.w;                              \
            _Pragma("unroll") for (int c = 0; c < 3; ++c) {                  \
                acc[0][c].x += a * W_[j * 3 + c].x;                          \
                acc[0][c].y += a * W_[j * 3 + c].y;                          \
                acc[0][c].z += a * W_[j * 3 + c].z;                          \
                acc[0][c].w += a * W_[j * 3 + c].w;                          \
                acc[1][c].x += b * W_[j * 3 + c].x;                          \
                acc[1][c].y += b * W_[j * 3 + c].y;                          \
                acc[1][c].z += b * W_[j * 3 + c].z;                          \
                acc[1][c].w += b * W_[j * 3 + c].w;                          \
            }                                                                \
        }                                                                    \
    }

__global__ __launch_bounds__(128) void gemm_norm_kernel(
    const float* __restrict__ h, const float* __restrict__ norm,
    const float* __restrict__ w, unsigned short* __restrict__ hwb)
{
    const int tid = threadIdx.x;
    const int rg  = tid >> 3;            // 0..15
    const int cg  = tid & 7;             // 0..7 -> channels cg*12 .. +11
    const int row0 = blockIdx.x * 32 + rg;
    const int row1 = row0 + 16;
    const int r0c = row0 < M_NODES ? row0 : M_NODES - 1;
    const int r1c = row1 < M_NODES ? row1 : M_NODES - 1;

    const float* __restrict__ hr0 = h + (size_t)r0c * KDIM;
    const float* __restrict__ hr1 = h + (size_t)r1c * KDIM;
    const float* __restrict__ wp  = w + cg * 12;

    float4 acc[2][3];
#pragma unroll
    for (int r = 0; r < 2; ++r)
#pragma unroll
        for (int c = 0; c < 3; ++c)
            acc[r][c] = make_float4(0.f, 0.f, 0.f, 0.f);

    float4 WA[12], WB[12], haA, hbA, haB, hbB;
    LOAD_SLOT(WA, haA, hbA, 0);

    for (int k = 0; k < KDIM; k += 8) {
        LOAD_SLOT(WB, haB, hbB, k + 4);
        FMA_SLOT(WA, haA, hbA);
        LOAD_SLOT(WA, haA, hbA, (k + 8) & (KDIM - 1));  // last iter: dummy (unused)
        FMA_SLOT(WB, haB, hbB);
    }

    // epilogue: *norm, pack bf16, store 3x uint2 per row
#pragma unroll
    for (int r = 0; r < 2; ++r) {
        int row = (r == 0) ? row0 : row1;
        if (row < M_NODES) {
            float nv = norm[row];
            float v[12];
#pragma unroll
            for (int c = 0; c < 3; ++c) {
                v[c * 4 + 0] = acc[r][c].x * nv;
                v[c * 4 + 1] = acc[r][c].y * nv;
                v[c * 4 + 2] = acc[r][c].z * nv;
                v[c * 4 + 3] = acc[r][c].w * nv;
            }
            uint2* p = reinterpret_cast<uint2*>(hwb + (size_t)row * NDIM + cg * 12);
            p[0] = make_uint2(pack2bf(v[0], v[1]), pack2bf(v[2], v[3]));
            p[1] = make_uint2(pack2bf(v[4], v[5]), pack2bf(v[6], v[7]));
            p[2] = make_uint2(pack2bf(v[8], v[9]), pack2bf(v[10], v[11]));
        }
    }
}

// -------- Kernel 2a: histogram of dst ----------------------------------
__global__ __launch_bounds__(256) void hist_kernel(
    const int* __restrict__ dst, int* __restrict__ cnt)
{
    int e = blockIdx.x * 256 + threadIdx.x;
    if (e < NEDGE) atomicAdd(&cnt[dst[e]], 1);
}

// -------- Kernel 2b: hierarchical exclusive scan -----------------------
__global__ __launch_bounds__(256) void scan1_kernel(
    const int* __restrict__ cnt, int* __restrict__ off, int* __restrict__ bsum)
{
    __shared__ int sh[256];
    const int t = threadIdx.x;
    const int i = blockIdx.x * 256 + t;
    int v = (i < M_NODES) ? cnt[i] : 0;
    sh[t] = v;
    __syncthreads();
    for (int st = 1; st < 256; st <<= 1) {
        int o = (t >= st) ? sh[t - st] : 0;
        __syncthreads();
        sh[t] += o;
        __syncthreads();
    }
    if (i < M_NODES) off[i] = sh[t] - v;
    if (t == 255) bsum[blockIdx.x] = sh[t];
}

__global__ __launch_bounds__(256) void scan2_kernel(
    const int* __restrict__ bsum, int* __restrict__ bbase, int* __restrict__ off)
{
    __shared__ int sh[256];
    const int t = threadIdx.x;
    int v = (t < NB_SCAN) ? bsum[t] : 0;
    sh[t] = v;
    __syncthreads();
    for (int st = 1; st < 256; st <<= 1) {
        int o = (t >= st) ? sh[t - st] : 0;
        __syncthreads();
        sh[t] += o;
        __syncthreads();
    }
    if (t < NB_SCAN) bbase[t] = sh[t] - v;
    if (t == NB_SCAN - 1) off[M_NODES] = sh[t];
}

__global__ __launch_bounds__(256) void addbase_kernel(
    int* __restrict__ off, const int* __restrict__ bbase)
{
    int i = blockIdx.x * 256 + threadIdx.x;
    if (i < M_NODES) off[i] += bbase[i >> 8];
}

// -------- Kernel 2c: bucket src ids by dst -----------------------------
__global__ __launch_bounds__(256) void build_kernel(
    const int* __restrict__ src, const int* __restrict__ dst,
    const int* __restrict__ off, int* __restrict__ cur,
    int* __restrict__ edge_src)
{
    int e = blockIdx.x * 256 + threadIdx.x;
    if (e >= NEDGE) return;
    int d = dst[e];
    int pos = atomicAdd(&cur[d], 1);
    edge_src[off[d] + pos] = src[e];
}

// -------- Kernel 3: gather-side segment sum + relu(agg*norm) -----------
// 12 threads = 12x8 bf16 channels of one dst node; 16 nodes per 192-block.
// Each lane: 16B uint4 gather per edge, unroll x4 for MLP.
#define ACC8(v)                                        \
    acc[0] += __uint_as_float((v).x << 16);            \
    acc[1] += __uint_as_float((v).x & 0xffff0000u);    \
    acc[2] += __uint_as_float((v).y << 16);            \
    acc[3] += __uint_as_float((v).y & 0xffff0000u);    \
    acc[4] += __uint_as_float((v).z << 16);            \
    acc[5] += __uint_as_float((v).z & 0xffff0000u);    \
    acc[6] += __uint_as_float((v).w << 16);            \
    acc[7] += __uint_as_float((v).w & 0xffff0000u);

__global__ __launch_bounds__(192) void aggregate_kernel(
    const unsigned short* __restrict__ hwb, const int* __restrict__ off,
    const int* __restrict__ edge_src, const float* __restrict__ norm,
    float* __restrict__ out)
{
    const int tid = threadIdx.x;
    const int n   = blockIdx.x * 16 + tid / 12;
    const int c8  = tid % 12;            // channels c8*8 .. +7
    if (n >= M_NODES) return;

    const int e0 = off[n];
    const int e1 = off[n + 1];
    float acc[8] = {0.f, 0.f, 0.f, 0.f, 0.f, 0.f, 0.f, 0.f};

    int e = e0;
    for (; e + 4 <= e1; e += 4) {
        int s0 = edge_src[e + 0];
        int s1 = edge_src[e + 1];
        int s2 = edge_src[e + 2];
        int s3 = edge_src[e + 3];
        uint4 v0 = *reinterpret_cast<const uint4*>(hwb + (size_t)s0 * NDIM + c8 * 8);
        uint4 v1 = *reinterpret_cast<const uint4*>(hwb + (size_t)s1 * NDIM + c8 * 8);
        uint4 v2 = *reinterpret_cast<const uint4*>(hwb + (size_t)s2 * NDIM + c8 * 8);
        uint4 v3 = *reinterpret_cast<const uint4*>(hwb + (size_t)s3 * NDIM + c8 * 8);
        ACC8(v0); ACC8(v1); ACC8(v2); ACC8(v3);
    }
    for (; e < e1; ++e) {
        int s = edge_src[e];
        uint4 v = *reinterpret_cast<const uint4*>(hwb + (size_t)s * NDIM + c8 * 8);
        ACC8(v);
    }

    const float nv = norm[n];
    float4 o0, o1;
    o0.x = fmaxf(acc[0] * nv, 0.f); o0.y = fmaxf(acc[1] * nv, 0.f);
    o0.z = fmaxf(acc[2] * nv, 0.f); o0.w = fmaxf(acc[3] * nv, 0.f);
    o1.x = fmaxf(acc[4] * nv, 0.f); o1.y = fmaxf(acc[5] * nv, 0.f);
    o1.z = fmaxf(acc[6] * nv, 0.f); o1.w = fmaxf(acc[7] * nv, 0.f);
    float4* po = reinterpret_cast<float4*>(out + (size_t)n * NDIM + c8 * 8);
    po[0] = o0; po[1] = o1;
}

extern "C" void kernel_launch(void* const* d_in, const int* in_sizes, int n_in,
                              void* d_out, int out_size, void* d_ws, size_t ws_size,
                              hipStream_t stream)
{
    const float* h    = (const float*)d_in[0];
    const float* norm = (const float*)d_in[1];
    const float* w    = (const float*)d_in[2];
    const int*   src  = (const int*)d_in[3];
    const int*   dst  = (const int*)d_in[4];
    float* out = (float*)d_out;

    // workspace layout
    unsigned short* hwb = (unsigned short*)d_ws;        // 50000*96 bf16 = 9.6 MB
    int* cnt      = (int*)(hwb + (size_t)M_NODES * NDIM);
    int* off      = cnt + 50000;                        // 50001 (+3 pad)
    int* cur      = off + 50004;
    int* bsum     = cur + 50000;                        // 256
    int* bbase    = bsum + 256;                         // 256
    int* edge_src = bbase + 256;                        // 800000

    hipMemsetAsync(cnt, 0, 50000 * sizeof(int), stream);
    hipMemsetAsync(cur, 0, 50000 * sizeof(int), stream);

    hist_kernel<<<(NEDGE + 255) / 256, 256, 0, stream>>>(dst, cnt);
    scan1_kernel<<<NB_SCAN, 256, 0, stream>>>(cnt, off, bsum);
    scan2_kernel<<<1, 256, 0, stream>>>(bsum, bbase, off);
    addbase_kernel<<<NB_SCAN, 256, 0, stream>>>(off, bbase);
    build_kernel<<<(NEDGE + 255) / 256, 256, 0, stream>>>(src, dst, off, cur, edge_src);

    gemm_norm_kernel<<<(M_NODES + 31) / 32, 128, 0, stream>>>(h, norm, w, hwb);

    aggregate_kernel<<<(M_NODES + 15) / 16, 192, 0, stream>>>(hwb, off, edge_src, norm, out);
}

// Round 5
// 143.467 us; speedup vs baseline: 7.6392x; 1.5019x over previous
//
#include <hip/hip_runtime.h>

#define M_NODES 50000
#define KDIM    256
#define NDIM    96
#define NEDGE   800000
#define NB_SCAN 196   // ceil(50000/256)
#define BM      64    // gemm rows per block

typedef short bf16x8 __attribute__((ext_vector_type(8)));   // 8 bf16 (4 VGPRs)
typedef float f32x4  __attribute__((ext_vector_type(4)));

// round-to-nearest-even f32 -> bf16 (as u16)
__device__ inline unsigned short f2bf(float x) {
    unsigned u = __float_as_uint(x);
    u = (u + 0x7fffu + ((u >> 16) & 1u)) >> 16;
    return (unsigned short)u;
}
__device__ inline unsigned pack2bf(float x, float y) {
    return (unsigned)f2bf(x) | ((unsigned)f2bf(y) << 16);
}

// -------- Kernel 0: Wt[n][k] = bf16(W[k][n]) ---------------------------
__global__ __launch_bounds__(256) void prep_w_kernel(
    const float* __restrict__ w, unsigned short* __restrict__ wt)
{
    int i = blockIdx.x * 256 + threadIdx.x;   // over 96*256
    if (i < KDIM * NDIM) {
        int n = i >> 8;        // 0..95
        int k = i & 255;       // 0..255
        wt[i] = f2bf(w[(size_t)k * NDIM + n]);
    }
}

// -------- Kernel 1: hwb = bf16((h @ W) * norm) via MFMA ----------------
// 256 thr = 4 waves; BM=64 rows/block; N=96 whole. LDS XOR-swizzled
// (byte ^= (row&7)<<4) so A/B ds_read_b128 are ~2-way (free).
__global__ __launch_bounds__(256) void gemm_mfma_kernel(
    const float* __restrict__ h, const float* __restrict__ norm,
    const unsigned short* __restrict__ wt, unsigned short* __restrict__ hwb)
{
    __shared__ unsigned short h_lds[BM * 256];   // 64 rows x 512B = 32 KB
    __shared__ unsigned short w_lds[96 * 256];   // 96 rows x 512B = 48 KB

    const int tid  = threadIdx.x;
    const int lane = tid & 63;
    const int wv   = tid >> 6;                   // 0..3
    const int row0 = blockIdx.x * BM;

    // stage Wt -> w_lds (swizzled), 12 x 16B per thread
#pragma unroll
    for (int it = 0; it < 12; ++it) {
        int idx = tid + it * 256;                // 0..3071
        int n   = idx >> 5;                      // 0..95
        int kb  = (idx & 31) * 16;               // byte in row
        uint4 v = *reinterpret_cast<const uint4*>(
            reinterpret_cast<const char*>(wt) + n * 512 + kb);
        *reinterpret_cast<uint4*>(
            reinterpret_cast<char*>(w_lds) + n * 512 + (kb ^ ((n & 7) << 4))) = v;
    }
    // stage h -> h_lds bf16 (swizzled), 16 x (4 f32 -> 8B) per thread
#pragma unroll
    for (int it = 0; it < 16; ++it) {
        int idx = tid + it * 256;                // 0..4095
        int r   = idx >> 6;                      // 0..63
        int c4  = idx & 63;                      // float4 within row
        int row = row0 + r;
        if (row >= M_NODES) row = M_NODES - 1;   // safe clamp
        float4 v = *reinterpret_cast<const float4*>(h + (size_t)row * KDIM + c4 * 4);
        uint2 p = make_uint2(pack2bf(v.x, v.y), pack2bf(v.z, v.w));
        *reinterpret_cast<uint2*>(
            reinterpret_cast<char*>(h_lds) + r * 512 + ((c4 * 8) ^ ((r & 7) << 4))) = p;
    }
    __syncthreads();

    f32x4 acc[6];
#pragma unroll
    for (int f = 0; f < 6; ++f) acc[f] = (f32x4){0.f, 0.f, 0.f, 0.f};

    const int ar   = wv * 16 + (lane & 15);      // A row in tile
    const int kgrp = (lane >> 4) * 16;           // byte offset of lane's 8 bf16

#pragma unroll
    for (int s = 0; s < 8; ++s) {
        const int kb = s * 64 + kgrp;            // byte offset of k-slice
        bf16x8 a = *reinterpret_cast<const bf16x8*>(
            reinterpret_cast<const char*>(h_lds) + ar * 512 + (kb ^ ((ar & 7) << 4)));
#pragma unroll
        for (int f = 0; f < 6; ++f) {
            int n = f * 16 + (lane & 15);
            bf16x8 b = *reinterpret_cast<const bf16x8*>(
                reinterpret_cast<const char*>(w_lds) + n * 512 + (kb ^ ((n & 7) << 4)));
            acc[f] = __builtin_amdgcn_mfma_f32_16x16x32_bf16(a, b, acc[f], 0, 0, 0);
        }
    }

    // epilogue: C/D layout col=lane&15, row=(lane>>4)*4+reg (m89-verified)
    const int crow = wv * 16 + (lane >> 4) * 4;
    const int ccol = lane & 15;
#pragma unroll
    for (int r = 0; r < 4; ++r) {
        int row = row0 + crow + r;
        if (row < M_NODES) {
            float nv = norm[row];
#pragma unroll
            for (int f = 0; f < 6; ++f)
                hwb[(size_t)row * NDIM + f * 16 + ccol] = f2bf(acc[f][r] * nv);
        }
    }
}

// -------- Kernel 2a: histogram of dst ----------------------------------
__global__ __launch_bounds__(256) void hist_kernel(
    const int* __restrict__ dst, int* __restrict__ cnt)
{
    int e = blockIdx.x * 256 + threadIdx.x;
    if (e < NEDGE) atomicAdd(&cnt[dst[e]], 1);
}

// -------- Kernel 2b: hierarchical exclusive scan -----------------------
__global__ __launch_bounds__(256) void scan1_kernel(
    const int* __restrict__ cnt, int* __restrict__ off, int* __restrict__ bsum)
{
    __shared__ int sh[256];
    const int t = threadIdx.x;
    const int i = blockIdx.x * 256 + t;
    int v = (i < M_NODES) ? cnt[i] : 0;
    sh[t] = v;
    __syncthreads();
    for (int st = 1; st < 256; st <<= 1) {
        int o = (t >= st) ? sh[t - st] : 0;
        __syncthreads();
        sh[t] += o;
        __syncthreads();
    }
    if (i < M_NODES) off[i] = sh[t] - v;
    if (t == 255) bsum[blockIdx.x] = sh[t];
}

__global__ __launch_bounds__(256) void scan2_kernel(
    const int* __restrict__ bsum, int* __restrict__ bbase, int* __restrict__ off)
{
    __shared__ int sh[256];
    const int t = threadIdx.x;
    int v = (t < NB_SCAN) ? bsum[t] : 0;
    sh[t] = v;
    __syncthreads();
    for (int st = 1; st < 256; st <<= 1) {
        int o = (t >= st) ? sh[t - st] : 0;
        __syncthreads();
        sh[t] += o;
        __syncthreads();
    }
    if (t < NB_SCAN) bbase[t] = sh[t] - v;
    if (t == NB_SCAN - 1) off[M_NODES] = sh[t];
}

__global__ __launch_bounds__(256) void addbase_kernel(
    int* __restrict__ off, const int* __restrict__ bbase)
{
    int i = blockIdx.x * 256 + threadIdx.x;
    if (i < M_NODES) off[i] += bbase[i >> 8];
}

// -------- Kernel 2c: bucket src ids by dst -----------------------------
__global__ __launch_bounds__(256) void build_kernel(
    const int* __restrict__ src, const int* __restrict__ dst,
    const int* __restrict__ off, int* __restrict__ cur,
    int* __restrict__ edge_src)
{
    int e = blockIdx.x * 256 + threadIdx.x;
    if (e >= NEDGE) return;
    int d = dst[e];
    int pos = atomicAdd(&cur[d], 1);
    edge_src[off[d] + pos] = src[e];
}

// -------- Kernel 3: gather-side segment sum + relu(agg*norm) -----------
#define ACC8(v)                                        \
    acc[0] += __uint_as_float((v).x << 16);            \
    acc[1] += __uint_as_float((v).x & 0xffff0000u);    \
    acc[2] += __uint_as_float((v).y << 16);            \
    acc[3] += __uint_as_float((v).y & 0xffff0000u);    \
    acc[4] += __uint_as_float((v).z << 16);            \
    acc[5] += __uint_as_float((v).z & 0xffff0000u);    \
    acc[6] += __uint_as_float((v).w << 16);            \
    acc[7] += __uint_as_float((v).w & 0xffff0000u);

__global__ __launch_bounds__(192) void aggregate_kernel(
    const unsigned short* __restrict__ hwb, const int* __restrict__ off,
    const int* __restrict__ edge_src, const float* __restrict__ norm,
    float* __restrict__ out)
{
    const int tid = threadIdx.x;
    const int n   = blockIdx.x * 16 + tid / 12;
    const int c8  = tid % 12;            // channels c8*8 .. +7
    if (n >= M_NODES) return;

    const int e0 = off[n];
    const int e1 = off[n + 1];
    float acc[8] = {0.f, 0.f, 0.f, 0.f, 0.f, 0.f, 0.f, 0.f};

    int e = e0;
    for (; e + 4 <= e1; e += 4) {
        int s0 = edge_src[e + 0];
        int s1 = edge_src[e + 1];
        int s2 = edge_src[e + 2];
        int s3 = edge_src[e + 3];
        uint4 v0 = *reinterpret_cast<const uint4*>(hwb + (size_t)s0 * NDIM + c8 * 8);
        uint4 v1 = *reinterpret_cast<const uint4*>(hwb + (size_t)s1 * NDIM + c8 * 8);
        uint4 v2 = *reinterpret_cast<const uint4*>(hwb + (size_t)s2 * NDIM + c8 * 8);
        uint4 v3 = *reinterpret_cast<const uint4*>(hwb + (size_t)s3 * NDIM + c8 * 8);
        ACC8(v0); ACC8(v1); ACC8(v2); ACC8(v3);
    }
    for (; e < e1; ++e) {
        int s = edge_src[e];
        uint4 v = *reinterpret_cast<const uint4*>(hwb + (size_t)s * NDIM + c8 * 8);
        ACC8(v);
    }

    const float nv = norm[n];
    float4 o0, o1;
    o0.x = fmaxf(acc[0] * nv, 0.f); o0.y = fmaxf(acc[1] * nv, 0.f);
    o0.z = fmaxf(acc[2] * nv, 0.f); o0.w = fmaxf(acc[3] * nv, 0.f);
    o1.x = fmaxf(acc[4] * nv, 0.f); o1.y = fmaxf(acc[5] * nv, 0.f);
    o1.z = fmaxf(acc[6] * nv, 0.f); o1.w = fmaxf(acc[7] * nv, 0.f);
    float4* po = reinterpret_cast<float4*>(out + (size_t)n * NDIM + c8 * 8);
    po[0] = o0; po[1] = o1;
}

extern "C" void kernel_launch(void* const* d_in, const int* in_sizes, int n_in,
                              void* d_out, int out_size, void* d_ws, size_t ws_size,
                              hipStream_t stream)
{
    const float* h    = (const float*)d_in[0];
    const float* norm = (const float*)d_in[1];
    const float* w    = (const float*)d_in[2];
    const int*   src  = (const int*)d_in[3];
    const int*   dst  = (const int*)d_in[4];
    float* out = (float*)d_out;

    // workspace layout
    unsigned short* hwb = (unsigned short*)d_ws;        // 50000*96 bf16 = 9.6 MB
    unsigned short* wt  = hwb + (size_t)M_NODES * NDIM; // 96*256 bf16 = 48 KB
    int* cnt      = (int*)(wt + KDIM * NDIM);
    int* off      = cnt + 50000;                        // 50001 (+3 pad)
    int* cur      = off + 50004;
    int* bsum     = cur + 50000;                        // 256
    int* bbase    = bsum + 256;                         // 256
    int* edge_src = bbase + 256;                        // 800000

    hipMemsetAsync(cnt, 0, 50000 * sizeof(int), stream);
    hipMemsetAsync(cur, 0, 50000 * sizeof(int), stream);

    prep_w_kernel<<<(KDIM * NDIM + 255) / 256, 256, 0, stream>>>(w, wt);
    hist_kernel<<<(NEDGE + 255) / 256, 256, 0, stream>>>(dst, cnt);
    scan1_kernel<<<NB_SCAN, 256, 0, stream>>>(cnt, off, bsum);
    scan2_kernel<<<1, 256, 0, stream>>>(bsum, bbase, off);
    addbase_kernel<<<NB_SCAN, 256, 0, stream>>>(off, bbase);
    build_kernel<<<(NEDGE + 255) / 256, 256, 0, stream>>>(src, dst, off, cur, edge_src);

    gemm_mfma_kernel<<<(M_NODES + BM - 1) / BM, 256, 0, stream>>>(h, norm, wt, hwb);

    aggregate_kernel<<<(M_NODES + 15) / 16, 192, 0, stream>>>(hwb, off, edge_src, norm, out);
}

// Round 6
// 103.928 us; speedup vs baseline: 10.5455x; 1.3804x over previous
//
#include <hip/hip_runtime.h>

#define M_NODES 50000
#define KDIM    256
#define NDIM    96
#define NEDGE   800000
#define BM      64     // gemm rows per block
#define NPB     256    // nodes per bucket
#define NBUCKET 196    // ceil(50000/256)
#define EPB     8192   // edges per bin_scatter block
#define NBLK_SC 98     // ceil(800000/8192)

typedef short bf16x8 __attribute__((ext_vector_type(8)));   // 8 bf16 (4 VGPRs)
typedef float f32x4  __attribute__((ext_vector_type(4)));

// round-to-nearest-even f32 -> bf16 (as u16)
__device__ inline unsigned short f2bf(float x) {
    unsigned u = __float_as_uint(x);
    u = (u + 0x7fffu + ((u >> 16) & 1u)) >> 16;
    return (unsigned short)u;
}
__device__ inline unsigned pack2bf(float x, float y) {
    return (unsigned)f2bf(x) | ((unsigned)f2bf(y) << 16);
}

// -------- Kernel 0: Wt[n][k] = bf16(W[k][n]) ---------------------------
__global__ __launch_bounds__(256) void prep_w_kernel(
    const float* __restrict__ w, unsigned short* __restrict__ wt)
{
    int i = blockIdx.x * 256 + threadIdx.x;   // over 96*256
    if (i < KDIM * NDIM) {
        int n = i >> 8;        // 0..95
        int k = i & 255;       // 0..255
        wt[i] = f2bf(w[(size_t)k * NDIM + n]);
    }
}

// -------- Kernel 1: hwb = bf16((h @ W) * norm) via MFMA ----------------
__global__ __launch_bounds__(256) void gemm_mfma_kernel(
    const float* __restrict__ h, const float* __restrict__ norm,
    const unsigned short* __restrict__ wt, unsigned short* __restrict__ hwb)
{
    __shared__ unsigned short h_lds[BM * 256];   // 64 rows x 512B = 32 KB
    __shared__ unsigned short w_lds[96 * 256];   // 96 rows x 512B = 48 KB

    const int tid  = threadIdx.x;
    const int lane = tid & 63;
    const int wv   = tid >> 6;                   // 0..3
    const int row0 = blockIdx.x * BM;

    // stage Wt -> w_lds (swizzled), 12 x 16B per thread
#pragma unroll
    for (int it = 0; it < 12; ++it) {
        int idx = tid + it * 256;                // 0..3071
        int n   = idx >> 5;                      // 0..95
        int kb  = (idx & 31) * 16;               // byte in row
        uint4 v = *reinterpret_cast<const uint4*>(
            reinterpret_cast<const char*>(wt) + n * 512 + kb);
        *reinterpret_cast<uint4*>(
            reinterpret_cast<char*>(w_lds) + n * 512 + (kb ^ ((n & 7) << 4))) = v;
    }
    // stage h -> h_lds bf16 (swizzled), 16 x (4 f32 -> 8B) per thread
#pragma unroll
    for (int it = 0; it < 16; ++it) {
        int idx = tid + it * 256;                // 0..4095
        int r   = idx >> 6;                      // 0..63
        int c4  = idx & 63;                      // float4 within row
        int row = row0 + r;
        if (row >= M_NODES) row = M_NODES - 1;   // safe clamp
        float4 v = *reinterpret_cast<const float4*>(h + (size_t)row * KDIM + c4 * 4);
        uint2 p = make_uint2(pack2bf(v.x, v.y), pack2bf(v.z, v.w));
        *reinterpret_cast<uint2*>(
            reinterpret_cast<char*>(h_lds) + r * 512 + ((c4 * 8) ^ ((r & 7) << 4))) = p;
    }
    __syncthreads();

    f32x4 acc[6];
#pragma unroll
    for (int f = 0; f < 6; ++f) acc[f] = (f32x4){0.f, 0.f, 0.f, 0.f};

    const int ar   = wv * 16 + (lane & 15);      // A row in tile
    const int kgrp = (lane >> 4) * 16;           // byte offset of lane's 8 bf16

#pragma unroll
    for (int s = 0; s < 8; ++s) {
        const int kb = s * 64 + kgrp;            // byte offset of k-slice
        bf16x8 a = *reinterpret_cast<const bf16x8*>(
            reinterpret_cast<const char*>(h_lds) + ar * 512 + (kb ^ ((ar & 7) << 4)));
#pragma unroll
        for (int f = 0; f < 6; ++f) {
            int n = f * 16 + (lane & 15);
            bf16x8 b = *reinterpret_cast<const bf16x8*>(
                reinterpret_cast<const char*>(w_lds) + n * 512 + (kb ^ ((n & 7) << 4)));
            acc[f] = __builtin_amdgcn_mfma_f32_16x16x32_bf16(a, b, acc[f], 0, 0, 0);
        }
    }

    // epilogue: C/D layout col=lane&15, row=(lane>>4)*4+reg
    const int crow = wv * 16 + (lane >> 4) * 4;
    const int ccol = lane & 15;
#pragma unroll
    for (int r = 0; r < 4; ++r) {
        int row = row0 + crow + r;
        if (row < M_NODES) {
            float nv = norm[row];
#pragma unroll
            for (int f = 0; f < 6; ++f)
                hwb[(size_t)row * NDIM + f * 16 + ccol] = f2bf(acc[f][r] * nv);
        }
    }
}

// -------- Kernel 2a: coarse bucket histogram (bucket = dst>>8) ---------
__global__ __launch_bounds__(256) void bucket_count_kernel(
    const int* __restrict__ dst, int* __restrict__ bcnt)
{
    __shared__ int cnt[NBUCKET];
    const int t = threadIdx.x;
    for (int i = t; i < NBUCKET; i += 256) cnt[i] = 0;
    __syncthreads();
    const int e0 = blockIdx.x * EPB;
    const int e1 = (e0 + EPB < NEDGE) ? e0 + EPB : NEDGE;
    for (int e = e0 + t; e < e1; e += 256)
        atomicAdd(&cnt[dst[e] >> 8], 1);
    __syncthreads();
    for (int i = t; i < NBUCKET; i += 256)
        if (cnt[i]) atomicAdd(&bcnt[i], cnt[i]);
}

// -------- Kernel 2b: scan bucket totals -> bases + cursors -------------
__global__ __launch_bounds__(256) void bucket_scan_kernel(
    const int* __restrict__ bcnt, int* __restrict__ bbase,
    int* __restrict__ gcursor, int* __restrict__ off)
{
    __shared__ int sh[256];
    const int t = threadIdx.x;
    int v = (t < NBUCKET) ? bcnt[t] : 0;
    sh[t] = v;
    __syncthreads();
    for (int st = 1; st < 256; st <<= 1) {
        int o = (t >= st) ? sh[t - st] : 0;
        __syncthreads();
        sh[t] += o;
        __syncthreads();
    }
    if (t < NBUCKET) {
        int ex = sh[t] - v;
        bbase[t]   = ex;
        gcursor[t] = ex;
    }
    if (t == 0) { bbase[NBUCKET] = NEDGE; off[M_NODES] = NEDGE; }
}

// -------- Kernel 2c: bin edges into bucket chunks (coalesced-ish) ------
// Each block: LDS-count its 8192 edges per bucket, reserve one contiguous
// chunk per bucket (1 global atomic each), then write packed
// (dst&255)<<16 | src u32s into its chunks -> block-local line-filling writes.
__global__ __launch_bounds__(256) void bin_scatter_kernel(
    const int* __restrict__ src, const int* __restrict__ dst,
    int* __restrict__ gcursor, unsigned* __restrict__ binned)
{
    __shared__ int cnt[NBUCKET];
    __shared__ int base[NBUCKET];
    const int t  = threadIdx.x;
    const int e0 = blockIdx.x * EPB;
    const int e1 = (e0 + EPB < NEDGE) ? e0 + EPB : NEDGE;

    for (int i = t; i < NBUCKET; i += 256) cnt[i] = 0;
    __syncthreads();
    for (int e = e0 + t; e < e1; e += 256)
        atomicAdd(&cnt[dst[e] >> 8], 1);
    __syncthreads();
    for (int i = t; i < NBUCKET; i += 256) {
        int c = cnt[i];
        base[i] = c ? atomicAdd(&gcursor[i], c) : 0;
    }
    __syncthreads();
    for (int i = t; i < NBUCKET; i += 256) cnt[i] = 0;  // reuse as cursor
    __syncthreads();
    for (int e = e0 + t; e < e1; e += 256) {
        int d = dst[e];
        int b = d >> 8;
        int pos = base[b] + atomicAdd(&cnt[b], 1);
        binned[pos] = ((unsigned)(d & 255) << 16) | (unsigned)src[e];
    }
}

// -------- Kernel 2d: per-bucket CSR finalize ---------------------------
// One block per bucket: per-node LDS count + scan -> off[]; then place
// src ids into the bucket's contiguous edge_src region.
__global__ __launch_bounds__(256) void csr_build_kernel(
    const unsigned* __restrict__ binned, const int* __restrict__ bbase,
    int* __restrict__ off, int* __restrict__ edge_src)
{
    __shared__ int cnt[NPB];
    __shared__ int pfx[NPB];
    const int b  = blockIdx.x;
    const int t  = threadIdx.x;
    const int e0 = bbase[b];
    const int e1 = bbase[b + 1];

    cnt[t] = 0;
    __syncthreads();
    for (int e = e0 + t; e < e1; e += 256)
        atomicAdd(&cnt[(binned[e] >> 16) & 255], 1);
    __syncthreads();
    int v = cnt[t];
    pfx[t] = v;
    __syncthreads();
    for (int st = 1; st < 256; st <<= 1) {
        int o = (t >= st) ? pfx[t - st] : 0;
        __syncthreads();
        pfx[t] += o;
        __syncthreads();
    }
    const int excl = pfx[t] - v;
    const int node = b * NPB + t;
    if (node < M_NODES) off[node] = e0 + excl;
    cnt[t] = excl;                 // reuse as cursor
    __syncthreads();
    for (int e = e0 + t; e < e1; e += 256) {
        unsigned pv = binned[e];
        int d   = (pv >> 16) & 255;
        int pos = atomicAdd(&cnt[d], 1);
        edge_src[e0 + pos] = (int)(pv & 0xffffu);
    }
}

// -------- Kernel 3: gather-side segment sum + relu(agg*norm) -----------
#define ACC8(v)                                        \
    acc[0] += __uint_as_float((v).x << 16);            \
    acc[1] += __uint_as_float((v).x & 0xffff0000u);    \
    acc[2] += __uint_as_float((v).y << 16);            \
    acc[3] += __uint_as_float((v).y & 0xffff0000u);    \
    acc[4] += __uint_as_float((v).z << 16);            \
    acc[5] += __uint_as_float((v).z & 0xffff0000u);    \
    acc[6] += __uint_as_float((v).w << 16);            \
    acc[7] += __uint_as_float((v).w & 0xffff0000u);

__global__ __launch_bounds__(192) void aggregate_kernel(
    const unsigned short* __restrict__ hwb, const int* __restrict__ off,
    const int* __restrict__ edge_src, const float* __restrict__ norm,
    float* __restrict__ out)
{
    const int tid = threadIdx.x;
    const int n   = blockIdx.x * 16 + tid / 12;
    const int c8  = tid % 12;            // channels c8*8 .. +7
    if (n >= M_NODES) return;

    const int e0 = off[n];
    const int e1 = off[n + 1];
    float acc[8] = {0.f, 0.f, 0.f, 0.f, 0.f, 0.f, 0.f, 0.f};

    int e = e0;
    for (; e + 4 <= e1; e += 4) {
        int s0 = edge_src[e + 0];
        int s1 = edge_src[e + 1];
        int s2 = edge_src[e + 2];
        int s3 = edge_src[e + 3];
        uint4 v0 = *reinterpret_cast<const uint4*>(hwb + (size_t)s0 * NDIM + c8 * 8);
        uint4 v1 = *reinterpret_cast<const uint4*>(hwb + (size_t)s1 * NDIM + c8 * 8);
        uint4 v2 = *reinterpret_cast<const uint4*>(hwb + (size_t)s2 * NDIM + c8 * 8);
        uint4 v3 = *reinterpret_cast<const uint4*>(hwb + (size_t)s3 * NDIM + c8 * 8);
        ACC8(v0); ACC8(v1); ACC8(v2); ACC8(v3);
    }
    for (; e < e1; ++e) {
        int s = edge_src[e];
        uint4 v = *reinterpret_cast<const uint4*>(hwb + (size_t)s * NDIM + c8 * 8);
        ACC8(v);
    }

    const float nv = norm[n];
    float4 o0, o1;
    o0.x = fmaxf(acc[0] * nv, 0.f); o0.y = fmaxf(acc[1] * nv, 0.f);
    o0.z = fmaxf(acc[2] * nv, 0.f); o0.w = fmaxf(acc[3] * nv, 0.f);
    o1.x = fmaxf(acc[4] * nv, 0.f); o1.y = fmaxf(acc[5] * nv, 0.f);
    o1.z = fmaxf(acc[6] * nv, 0.f); o1.w = fmaxf(acc[7] * nv, 0.f);
    float4* po = reinterpret_cast<float4*>(out + (size_t)n * NDIM + c8 * 8);
    po[0] = o0; po[1] = o1;
}

extern "C" void kernel_launch(void* const* d_in, const int* in_sizes, int n_in,
                              void* d_out, int out_size, void* d_ws, size_t ws_size,
                              hipStream_t stream)
{
    const float* h    = (const float*)d_in[0];
    const float* norm = (const float*)d_in[1];
    const float* w    = (const float*)d_in[2];
    const int*   src  = (const int*)d_in[3];
    const int*   dst  = (const int*)d_in[4];
    float* out = (float*)d_out;

    // workspace layout
    unsigned short* hwb = (unsigned short*)d_ws;        // 50000*96 bf16 = 9.6 MB
    unsigned short* wt  = hwb + (size_t)M_NODES * NDIM; // 96*256 bf16 = 48 KB
    int* off      = (int*)(wt + KDIM * NDIM);           // 50001 (+3 pad)
    int* bcnt     = off + 50004;                        // 196
    int* bbase    = bcnt + 200;                         // 197 (+pad)
    int* gcursor  = bbase + 200;                        // 196
    unsigned* binned = (unsigned*)(gcursor + 200);      // 800000
    int* edge_src = (int*)(binned + NEDGE);             // 800000

    hipMemsetAsync(bcnt, 0, NBUCKET * sizeof(int), stream);

    prep_w_kernel<<<(KDIM * NDIM + 255) / 256, 256, 0, stream>>>(w, wt);
    bucket_count_kernel<<<NBLK_SC, 256, 0, stream>>>(dst, bcnt);
    bucket_scan_kernel<<<1, 256, 0, stream>>>(bcnt, bbase, gcursor, off);
    bin_scatter_kernel<<<NBLK_SC, 256, 0, stream>>>(src, dst, gcursor, binned);
    csr_build_kernel<<<NBUCKET, 256, 0, stream>>>(binned, bbase, off, edge_src);

    gemm_mfma_kernel<<<(M_NODES + BM - 1) / BM, 256, 0, stream>>>(h, norm, wt, hwb);

    aggregate_kernel<<<(M_NODES + 15) / 16, 192, 0, stream>>>(hwb, off, edge_src, norm, out);
}

// Round 7
// 102.035 us; speedup vs baseline: 10.7411x; 1.0186x over previous
//
#include <hip/hip_runtime.h>

#define M_NODES 50000
#define KDIM    256
#define NDIM    96
#define NEDGE   800000
#define BM      64     // gemm rows per block
#define NPB     256    // nodes per bucket
#define NBUCKET 196    // ceil(50000/256)
#define EPB     2048   // edges per bucket_count/bin_scatter block
#define NBLK_SC 391    // ceil(800000/2048)

typedef short bf16x8 __attribute__((ext_vector_type(8)));   // 8 bf16 (4 VGPRs)
typedef float f32x4  __attribute__((ext_vector_type(4)));

// round-to-nearest-even f32 -> bf16 (as u16)
__device__ inline unsigned short f2bf(float x) {
    unsigned u = __float_as_uint(x);
    u = (u + 0x7fffu + ((u >> 16) & 1u)) >> 16;
    return (unsigned short)u;
}
__device__ inline unsigned pack2bf(float x, float y) {
    return (unsigned)f2bf(x) | ((unsigned)f2bf(y) << 16);
}

// -------- Kernel 0: Wt[n][k] = bf16(W[k][n]) ---------------------------
__global__ __launch_bounds__(256) void prep_w_kernel(
    const float* __restrict__ w, unsigned short* __restrict__ wt)
{
    int i = blockIdx.x * 256 + threadIdx.x;   // over 96*256
    if (i < KDIM * NDIM) {
        int n = i >> 8;        // 0..95
        int k = i & 255;       // 0..255
        wt[i] = f2bf(w[(size_t)k * NDIM + n]);
    }
}

// -------- Kernel 1: hwb = bf16((h @ W) * norm) via MFMA ----------------
// A (h rows) loaded global->reg with inline f32->bf16 cvt (each element
// consumed by exactly one wave -> no LDS reuse to exploit). W in swizzled
// LDS (staged once, reused by all 4 waves). One barrier total.
__global__ __launch_bounds__(256) void gemm_mfma_kernel(
    const float* __restrict__ h, const float* __restrict__ norm,
    const unsigned short* __restrict__ wt, unsigned short* __restrict__ hwb)
{
    __shared__ unsigned short w_lds[96 * 256];   // 96 rows x 512B = 48 KB

    const int tid  = threadIdx.x;
    const int lane = tid & 63;
    const int wv   = tid >> 6;                   // 0..3
    const int row0 = blockIdx.x * BM;

    // stage Wt -> w_lds (swizzled), 12 x 16B per thread
#pragma unroll
    for (int it = 0; it < 12; ++it) {
        int idx = tid + it * 256;                // 0..3071
        int n   = idx >> 5;                      // 0..95
        int kb  = (idx & 31) * 16;               // byte in row
        uint4 v = *reinterpret_cast<const uint4*>(
            reinterpret_cast<const char*>(wt) + n * 512 + kb);
        *reinterpret_cast<uint4*>(
            reinterpret_cast<char*>(w_lds) + n * 512 + (kb ^ ((n & 7) << 4))) = v;
    }
    __syncthreads();

    f32x4 acc[6];
#pragma unroll
    for (int f = 0; f < 6; ++f) acc[f] = (f32x4){0.f, 0.f, 0.f, 0.f};

    const int ar  = wv * 16 + (lane & 15);       // A row within tile
    const int kg  = lane >> 4;                   // 0..3 (8-elem k-group)
    int arow = row0 + ar;
    if (arow >= M_NODES) arow = M_NODES - 1;     // clamp; results discarded
    const float* __restrict__ hrow = h + (size_t)arow * KDIM;

#pragma unroll
    for (int s = 0; s < 8; ++s) {
        // A: 8 f32 -> bf16x8 in regs
        const int k0 = s * 32 + kg * 8;
        float4 p = *reinterpret_cast<const float4*>(hrow + k0);
        float4 q = *reinterpret_cast<const float4*>(hrow + k0 + 4);
        union { bf16x8 v; unsigned u[4]; } a;
        a.u[0] = pack2bf(p.x, p.y);
        a.u[1] = pack2bf(p.z, p.w);
        a.u[2] = pack2bf(q.x, q.y);
        a.u[3] = pack2bf(q.z, q.w);

        const int kb = s * 64 + kg * 16;         // byte offset of k-slice
#pragma unroll
        for (int f = 0; f < 6; ++f) {
            int n = f * 16 + (lane & 15);
            bf16x8 b = *reinterpret_cast<const bf16x8*>(
                reinterpret_cast<const char*>(w_lds) + n * 512 + (kb ^ ((n & 7) << 4)));
            acc[f] = __builtin_amdgcn_mfma_f32_16x16x32_bf16(a.v, b, acc[f], 0, 0, 0);
        }
    }

    // epilogue: C/D layout col=lane&15, row=(lane>>4)*4+reg
    const int crow = wv * 16 + (lane >> 4) * 4;
    const int ccol = lane & 15;
#pragma unroll
    for (int r = 0; r < 4; ++r) {
        int row = row0 + crow + r;
        if (row < M_NODES) {
            float nv = norm[row];
#pragma unroll
            for (int f = 0; f < 6; ++f)
                hwb[(size_t)row * NDIM + f * 16 + ccol] = f2bf(acc[f][r] * nv);
        }
    }
}

// -------- Kernel 2a: coarse bucket histogram (bucket = dst>>8) ---------
__global__ __launch_bounds__(256) void bucket_count_kernel(
    const int* __restrict__ dst, int* __restrict__ bcnt)
{
    __shared__ int cnt[NBUCKET];
    const int t = threadIdx.x;
    for (int i = t; i < NBUCKET; i += 256) cnt[i] = 0;
    __syncthreads();
    const int e0 = blockIdx.x * EPB;
    const int e1 = (e0 + EPB < NEDGE) ? e0 + EPB : NEDGE;
    for (int e = e0 + t; e < e1; e += 256)
        atomicAdd(&cnt[dst[e] >> 8], 1);
    __syncthreads();
    for (int i = t; i < NBUCKET; i += 256)
        if (cnt[i]) atomicAdd(&bcnt[i], cnt[i]);
}

// -------- Kernel 2b: scan bucket totals -> bases + cursors -------------
__global__ __launch_bounds__(256) void bucket_scan_kernel(
    const int* __restrict__ bcnt, int* __restrict__ bbase,
    int* __restrict__ gcursor, int* __restrict__ off)
{
    __shared__ int sh[256];
    const int t = threadIdx.x;
    int v = (t < NBUCKET) ? bcnt[t] : 0;
    sh[t] = v;
    __syncthreads();
    for (int st = 1; st < 256; st <<= 1) {
        int o = (t >= st) ? sh[t - st] : 0;
        __syncthreads();
        sh[t] += o;
        __syncthreads();
    }
    if (t < NBUCKET) {
        int ex = sh[t] - v;
        bbase[t]   = ex;
        gcursor[t] = ex;
    }
    if (t == 0) { bbase[NBUCKET] = NEDGE; off[M_NODES] = NEDGE; }
}

// -------- Kernel 2c: bin edges into bucket chunks ----------------------
__global__ __launch_bounds__(256) void bin_scatter_kernel(
    const int* __restrict__ src, const int* __restrict__ dst,
    int* __restrict__ gcursor, unsigned* __restrict__ binned)
{
    __shared__ int cnt[NBUCKET];
    __shared__ int base[NBUCKET];
    const int t  = threadIdx.x;
    const int e0 = blockIdx.x * EPB;
    const int e1 = (e0 + EPB < NEDGE) ? e0 + EPB : NEDGE;

    for (int i = t; i < NBUCKET; i += 256) cnt[i] = 0;
    __syncthreads();
    for (int e = e0 + t; e < e1; e += 256)
        atomicAdd(&cnt[dst[e] >> 8], 1);
    __syncthreads();
    for (int i = t; i < NBUCKET; i += 256) {
        int c = cnt[i];
        base[i] = c ? atomicAdd(&gcursor[i], c) : 0;
    }
    __syncthreads();
    for (int i = t; i < NBUCKET; i += 256) cnt[i] = 0;  // reuse as cursor
    __syncthreads();
    for (int e = e0 + t; e < e1; e += 256) {
        int d = dst[e];
        int b = d >> 8;
        int pos = base[b] + atomicAdd(&cnt[b], 1);
        binned[pos] = ((unsigned)(d & 255) << 16) | (unsigned)src[e];  // src<65536 ok
    }
}

// -------- Kernel 2d: per-bucket CSR finalize ---------------------------
__global__ __launch_bounds__(256) void csr_build_kernel(
    const unsigned* __restrict__ binned, const int* __restrict__ bbase,
    int* __restrict__ off, int* __restrict__ edge_src)
{
    __shared__ int cnt[NPB];
    __shared__ int pfx[NPB];
    const int b  = blockIdx.x;
    const int t  = threadIdx.x;
    const int e0 = bbase[b];
    const int e1 = bbase[b + 1];

    cnt[t] = 0;
    __syncthreads();
    for (int e = e0 + t; e < e1; e += 256)
        atomicAdd(&cnt[(binned[e] >> 16) & 255], 1);
    __syncthreads();
    int v = cnt[t];
    pfx[t] = v;
    __syncthreads();
    for (int st = 1; st < 256; st <<= 1) {
        int o = (t >= st) ? pfx[t - st] : 0;
        __syncthreads();
        pfx[t] += o;
        __syncthreads();
    }
    const int excl = pfx[t] - v;
    const int node = b * NPB + t;
    if (node < M_NODES) off[node] = e0 + excl;
    cnt[t] = excl;                 // reuse as cursor
    __syncthreads();
    for (int e = e0 + t; e < e1; e += 256) {
        unsigned pv = binned[e];
        int d   = (pv >> 16) & 255;
        int pos = atomicAdd(&cnt[d], 1);
        edge_src[e0 + pos] = (int)(pv & 0xffffu);
    }
}

// -------- Kernel 3: gather-side segment sum + relu(agg*norm) -----------
#define ACC8(v)                                        \
    acc[0] += __uint_as_float((v).x << 16);            \
    acc[1] += __uint_as_float((v).x & 0xffff0000u);    \
    acc[2] += __uint_as_float((v).y << 16);            \
    acc[3] += __uint_as_float((v).y & 0xffff0000u);    \
    acc[4] += __uint_as_float((v).z << 16);            \
    acc[5] += __uint_as_float((v).z & 0xffff0000u);    \
    acc[6] += __uint_as_float((v).w << 16);            \
    acc[7] += __uint_as_float((v).w & 0xffff0000u);

__global__ __launch_bounds__(192) void aggregate_kernel(
    const unsigned short* __restrict__ hwb, const int* __restrict__ off,
    const int* __restrict__ edge_src, const float* __restrict__ norm,
    float* __restrict__ out)
{
    const int tid = threadIdx.x;
    const int n   = blockIdx.x * 16 + tid / 12;
    const int c8  = tid % 12;            // channels c8*8 .. +7
    if (n >= M_NODES) return;

    const int e0 = off[n];
    const int e1 = off[n + 1];
    float acc[8] = {0.f, 0.f, 0.f, 0.f, 0.f, 0.f, 0.f, 0.f};

    int e = e0;
    for (; e + 4 <= e1; e += 4) {
        int s0 = edge_src[e + 0];
        int s1 = edge_src[e + 1];
        int s2 = edge_src[e + 2];
        int s3 = edge_src[e + 3];
        uint4 v0 = *reinterpret_cast<const uint4*>(hwb + (size_t)s0 * NDIM + c8 * 8);
        uint4 v1 = *reinterpret_cast<const uint4*>(hwb + (size_t)s1 * NDIM + c8 * 8);
        uint4 v2 = *reinterpret_cast<const uint4*>(hwb + (size_t)s2 * NDIM + c8 * 8);
        uint4 v3 = *reinterpret_cast<const uint4*>(hwb + (size_t)s3 * NDIM + c8 * 8);
        ACC8(v0); ACC8(v1); ACC8(v2); ACC8(v3);
    }
    for (; e < e1; ++e) {
        int s = edge_src[e];
        uint4 v = *reinterpret_cast<const uint4*>(hwb + (size_t)s * NDIM + c8 * 8);
        ACC8(v);
    }

    const float nv = norm[n];
    float4 o0, o1;
    o0.x = fmaxf(acc[0] * nv, 0.f); o0.y = fmaxf(acc[1] * nv, 0.f);
    o0.z = fmaxf(acc[2] * nv, 0.f); o0.w = fmaxf(acc[3] * nv, 0.f);
    o1.x = fmaxf(acc[4] * nv, 0.f); o1.y = fmaxf(acc[5] * nv, 0.f);
    o1.z = fmaxf(acc[6] * nv, 0.f); o1.w = fmaxf(acc[7] * nv, 0.f);
    float4* po = reinterpret_cast<float4*>(out + (size_t)n * NDIM + c8 * 8);
    po[0] = o0; po[1] = o1;
}

extern "C" void kernel_launch(void* const* d_in, const int* in_sizes, int n_in,
                              void* d_out, int out_size, void* d_ws, size_t ws_size,
                              hipStream_t stream)
{
    const float* h    = (const float*)d_in[0];
    const float* norm = (const float*)d_in[1];
    const float* w    = (const float*)d_in[2];
    const int*   src  = (const int*)d_in[3];
    const int*   dst  = (const int*)d_in[4];
    float* out = (float*)d_out;

    // workspace layout
    unsigned short* hwb = (unsigned short*)d_ws;        // 50000*96 bf16 = 9.6 MB
    unsigned short* wt  = hwb + (size_t)M_NODES * NDIM; // 96*256 bf16 = 48 KB
    int* off      = (int*)(wt + KDIM * NDIM);           // 50001 (+3 pad)
    int* bcnt     = off + 50004;                        // 196
    int* bbase    = bcnt + 200;                         // 197 (+pad)
    int* gcursor  = bbase + 200;                        // 196
    unsigned* binned = (unsigned*)(gcursor + 200);      // 800000
    int* edge_src = (int*)(binned + NEDGE);             // 800000

    hipMemsetAsync(bcnt, 0, NBUCKET * sizeof(int), stream);

    prep_w_kernel<<<(KDIM * NDIM + 255) / 256, 256, 0, stream>>>(w, wt);
    bucket_count_kernel<<<NBLK_SC, 256, 0, stream>>>(dst, bcnt);
    bucket_scan_kernel<<<1, 256, 0, stream>>>(bcnt, bbase, gcursor, off);
    bin_scatter_kernel<<<NBLK_SC, 256, 0, stream>>>(src, dst, gcursor, binned);
    csr_build_kernel<<<NBUCKET, 256, 0, stream>>>(binned, bbase, off, edge_src);

    gemm_mfma_kernel<<<(M_NODES + BM - 1) / BM, 256, 0, stream>>>(h, norm, wt, hwb);

    aggregate_kernel<<<(M_NODES + 15) / 16, 192, 0, stream>>>(hwb, off, edge_src, norm, out);
}

// Round 8
// 99.307 us; speedup vs baseline: 11.0362x; 1.0275x over previous
//
#include <hip/hip_runtime.h>

#define M_NODES 50000
#define KDIM    256
#define NDIM    96
#define NEDGE   800000
#define BM      64     // gemm rows per block
#define NPB     256    // nodes per bucket
#define NBUCKET 196    // ceil(50000/256)
#define EPB     2048   // edges per bucket_count/bin_scatter block
#define NBLK_SC 391    // ceil(800000/2048)

typedef short bf16x8 __attribute__((ext_vector_type(8)));   // 8 bf16 (4 VGPRs)
typedef float f32x4  __attribute__((ext_vector_type(4)));

// round-to-nearest-even f32 -> bf16 (as u16)
__device__ inline unsigned short f2bf(float x) {
    unsigned u = __float_as_uint(x);
    u = (u + 0x7fffu + ((u >> 16) & 1u)) >> 16;
    return (unsigned short)u;
}
__device__ inline unsigned pack2bf(float x, float y) {
    return (unsigned)f2bf(x) | ((unsigned)f2bf(y) << 16);
}

// -------- Kernel 0: Wt[n][k] = bf16(W[k][n]); block 0 zeros bcnt -------
__global__ __launch_bounds__(256) void prep_w_kernel(
    const float* __restrict__ w, unsigned short* __restrict__ wt,
    int* __restrict__ bcnt)
{
    if (blockIdx.x == 0 && threadIdx.x < NBUCKET)
        bcnt[threadIdx.x] = 0;            // replaces 40us fillBuffer dispatch
    int i = blockIdx.x * 256 + threadIdx.x;   // over 96*256
    if (i < KDIM * NDIM) {
        int n = i >> 8;        // 0..95
        int k = i & 255;       // 0..255
        wt[i] = f2bf(w[(size_t)k * NDIM + n]);
    }
}

// -------- Kernel 1: hwb = bf16((h @ W) * norm) via MFMA ----------------
// A (h rows) loaded global->reg with inline f32->bf16 cvt; W in swizzled
// LDS (staged once, reused by all 4 waves). One barrier total.
__global__ __launch_bounds__(256) void gemm_mfma_kernel(
    const float* __restrict__ h, const float* __restrict__ norm,
    const unsigned short* __restrict__ wt, unsigned short* __restrict__ hwb)
{
    __shared__ unsigned short w_lds[96 * 256];   // 96 rows x 512B = 48 KB

    const int tid  = threadIdx.x;
    const int lane = tid & 63;
    const int wv   = tid >> 6;                   // 0..3
    const int row0 = blockIdx.x * BM;

    // stage Wt -> w_lds (swizzled), 12 x 16B per thread
#pragma unroll
    for (int it = 0; it < 12; ++it) {
        int idx = tid + it * 256;                // 0..3071
        int n   = idx >> 5;                      // 0..95
        int kb  = (idx & 31) * 16;               // byte in row
        uint4 v = *reinterpret_cast<const uint4*>(
            reinterpret_cast<const char*>(wt) + n * 512 + kb);
        *reinterpret_cast<uint4*>(
            reinterpret_cast<char*>(w_lds) + n * 512 + (kb ^ ((n & 7) << 4))) = v;
    }
    __syncthreads();

    f32x4 acc[6];
#pragma unroll
    for (int f = 0; f < 6; ++f) acc[f] = (f32x4){0.f, 0.f, 0.f, 0.f};

    const int ar  = wv * 16 + (lane & 15);       // A row within tile
    const int kg  = lane >> 4;                   // 0..3 (8-elem k-group)
    int arow = row0 + ar;
    if (arow >= M_NODES) arow = M_NODES - 1;     // clamp; results discarded
    const float* __restrict__ hrow = h + (size_t)arow * KDIM;

#pragma unroll
    for (int s = 0; s < 8; ++s) {
        // A: 8 f32 -> bf16x8 in regs
        const int k0 = s * 32 + kg * 8;
        float4 p = *reinterpret_cast<const float4*>(hrow + k0);
        float4 q = *reinterpret_cast<const float4*>(hrow + k0 + 4);
        union { bf16x8 v; unsigned u[4]; } a;
        a.u[0] = pack2bf(p.x, p.y);
        a.u[1] = pack2bf(p.z, p.w);
        a.u[2] = pack2bf(q.x, q.y);
        a.u[3] = pack2bf(q.z, q.w);

        const int kb = s * 64 + kg * 16;         // byte offset of k-slice
#pragma unroll
        for (int f = 0; f < 6; ++f) {
            int n = f * 16 + (lane & 15);
            bf16x8 b = *reinterpret_cast<const bf16x8*>(
                reinterpret_cast<const char*>(w_lds) + n * 512 + (kb ^ ((n & 7) << 4)));
            acc[f] = __builtin_amdgcn_mfma_f32_16x16x32_bf16(a.v, b, acc[f], 0, 0, 0);
        }
    }

    // epilogue: C/D layout col=lane&15, row=(lane>>4)*4+reg
    const int crow = wv * 16 + (lane >> 4) * 4;
    const int ccol = lane & 15;
#pragma unroll
    for (int r = 0; r < 4; ++r) {
        int row = row0 + crow + r;
        if (row < M_NODES) {
            float nv = norm[row];
#pragma unroll
            for (int f = 0; f < 6; ++f)
                hwb[(size_t)row * NDIM + f * 16 + ccol] = f2bf(acc[f][r] * nv);
        }
    }
}

// -------- Kernel 2a: coarse bucket histogram (bucket = dst>>8) ---------
__global__ __launch_bounds__(256) void bucket_count_kernel(
    const int* __restrict__ dst, int* __restrict__ bcnt)
{
    __shared__ int cnt[NBUCKET];
    const int t = threadIdx.x;
    for (int i = t; i < NBUCKET; i += 256) cnt[i] = 0;
    __syncthreads();
    const int e0 = blockIdx.x * EPB;
    const int e1 = (e0 + EPB < NEDGE) ? e0 + EPB : NEDGE;
    for (int e = e0 + t; e < e1; e += 256)
        atomicAdd(&cnt[dst[e] >> 8], 1);
    __syncthreads();
    for (int i = t; i < NBUCKET; i += 256)
        if (cnt[i]) atomicAdd(&bcnt[i], cnt[i]);
}

// -------- Kernel 2b: scan bucket totals -> bases + cursors -------------
__global__ __launch_bounds__(256) void bucket_scan_kernel(
    const int* __restrict__ bcnt, int* __restrict__ bbase,
    int* __restrict__ gcursor, int* __restrict__ off)
{
    __shared__ int sh[256];
    const int t = threadIdx.x;
    int v = (t < NBUCKET) ? bcnt[t] : 0;
    sh[t] = v;
    __syncthreads();
    for (int st = 1; st < 256; st <<= 1) {
        int o = (t >= st) ? sh[t - st] : 0;
        __syncthreads();
        sh[t] += o;
        __syncthreads();
    }
    if (t < NBUCKET) {
        int ex = sh[t] - v;
        bbase[t]   = ex;
        gcursor[t] = ex;
    }
    if (t == 0) { bbase[NBUCKET] = NEDGE; off[M_NODES] = NEDGE; }
}

// -------- Kernel 2c: bin edges into bucket chunks ----------------------
__global__ __launch_bounds__(256) void bin_scatter_kernel(
    const int* __restrict__ src, const int* __restrict__ dst,
    int* __restrict__ gcursor, unsigned* __restrict__ binned)
{
    __shared__ int cnt[NBUCKET];
    __shared__ int base[NBUCKET];
    const int t  = threadIdx.x;
    const int e0 = blockIdx.x * EPB;
    const int e1 = (e0 + EPB < NEDGE) ? e0 + EPB : NEDGE;

    for (int i = t; i < NBUCKET; i += 256) cnt[i] = 0;
    __syncthreads();
    for (int e = e0 + t; e < e1; e += 256)
        atomicAdd(&cnt[dst[e] >> 8], 1);
    __syncthreads();
    for (int i = t; i < NBUCKET; i += 256) {
        int c = cnt[i];
        base[i] = c ? atomicAdd(&gcursor[i], c) : 0;
    }
    __syncthreads();
    for (int i = t; i < NBUCKET; i += 256) cnt[i] = 0;  // reuse as cursor
    __syncthreads();
    for (int e = e0 + t; e < e1; e += 256) {
        int d = dst[e];
        int b = d >> 8;
        int pos = base[b] + atomicAdd(&cnt[b], 1);
        binned[pos] = ((unsigned)(d & 255) << 16) | (unsigned)src[e];  // src<65536 ok
    }
}

// -------- Kernel 2d: per-bucket CSR finalize ---------------------------
__global__ __launch_bounds__(256) void csr_build_kernel(
    const unsigned* __restrict__ binned, const int* __restrict__ bbase,
    int* __restrict__ off, int* __restrict__ edge_src)
{
    __shared__ int cnt[NPB];
    __shared__ int pfx[NPB];
    const int b  = blockIdx.x;
    const int t  = threadIdx.x;
    const int e0 = bbase[b];
    const int e1 = bbase[b + 1];

    cnt[t] = 0;
    __syncthreads();
    for (int e = e0 + t; e < e1; e += 256)
        atomicAdd(&cnt[(binned[e] >> 16) & 255], 1);
    __syncthreads();
    int v = cnt[t];
    pfx[t] = v;
    __syncthreads();
    for (int st = 1; st < 256; st <<= 1) {
        int o = (t >= st) ? pfx[t - st] : 0;
        __syncthreads();
        pfx[t] += o;
        __syncthreads();
    }
    const int excl = pfx[t] - v;
    const int node = b * NPB + t;
    if (node < M_NODES) off[node] = e0 + excl;
    cnt[t] = excl;                 // reuse as cursor
    __syncthreads();
    for (int e = e0 + t; e < e1; e += 256) {
        unsigned pv = binned[e];
        int d   = (pv >> 16) & 255;
        int pos = atomicAdd(&cnt[d], 1);
        edge_src[e0 + pos] = (int)(pv & 0xffffu);
    }
}

// -------- Kernel 3: gather-side segment sum + relu(agg*norm) -----------
#define ACC8(v)                                        \
    acc[0] += __uint_as_float((v).x << 16);            \
    acc[1] += __uint_as_float((v).x & 0xffff0000u);    \
    acc[2] += __uint_as_float((v).y << 16);            \
    acc[3] += __uint_as_float((v).y & 0xffff0000u);    \
    acc[4] += __uint_as_float((v).z << 16);            \
    acc[5] += __uint_as_float((v).z & 0xffff0000u);    \
    acc[6] += __uint_as_float((v).w << 16);            \
    acc[7] += __uint_as_float((v).w & 0xffff0000u);

__global__ __launch_bounds__(192) void aggregate_kernel(
    const unsigned short* __restrict__ hwb, const int* __restrict__ off,
    const int* __restrict__ edge_src, const float* __restrict__ norm,
    float* __restrict__ out)
{
    const int tid = threadIdx.x;
    const int n   = blockIdx.x * 16 + tid / 12;
    const int c8  = tid % 12;            // channels c8*8 .. +7
    if (n >= M_NODES) return;

    const int e0 = off[n];
    const int e1 = off[n + 1];
    float acc[8] = {0.f, 0.f, 0.f, 0.f, 0.f, 0.f, 0.f, 0.f};

    int e = e0;
    for (; e + 4 <= e1; e += 4) {
        int s0 = edge_src[e + 0];
        int s1 = edge_src[e + 1];
        int s2 = edge_src[e + 2];
        int s3 = edge_src[e + 3];
        uint4 v0 = *reinterpret_cast<const uint4*>(hwb + (size_t)s0 * NDIM + c8 * 8);
        uint4 v1 = *reinterpret_cast<const uint4*>(hwb + (size_t)s1 * NDIM + c8 * 8);
        uint4 v2 = *reinterpret_cast<const uint4*>(hwb + (size_t)s2 * NDIM + c8 * 8);
        uint4 v3 = *reinterpret_cast<const uint4*>(hwb + (size_t)s3 * NDIM + c8 * 8);
        ACC8(v0); ACC8(v1); ACC8(v2); ACC8(v3);
    }
    for (; e < e1; ++e) {
        int s = edge_src[e];
        uint4 v = *reinterpret_cast<const uint4*>(hwb + (size_t)s * NDIM + c8 * 8);
        ACC8(v);
    }

    const float nv = norm[n];
    float4 o0, o1;
    o0.x = fmaxf(acc[0] * nv, 0.f); o0.y = fmaxf(acc[1] * nv, 0.f);
    o0.z = fmaxf(acc[2] * nv, 0.f); o0.w = fmaxf(acc[3] * nv, 0.f);
    o1.x = fmaxf(acc[4] * nv, 0.f); o1.y = fmaxf(acc[5] * nv, 0.f);
    o1.z = fmaxf(acc[6] * nv, 0.f); o1.w = fmaxf(acc[7] * nv, 0.f);
    float4* po = reinterpret_cast<float4*>(out + (size_t)n * NDIM + c8 * 8);
    po[0] = o0; po[1] = o1;
}

extern "C" void kernel_launch(void* const* d_in, const int* in_sizes, int n_in,
                              void* d_out, int out_size, void* d_ws, size_t ws_size,
                              hipStream_t stream)
{
    const float* h    = (const float*)d_in[0];
    const float* norm = (const float*)d_in[1];
    const float* w    = (const float*)d_in[2];
    const int*   src  = (const int*)d_in[3];
    const int*   dst  = (const int*)d_in[4];
    float* out = (float*)d_out;

    // workspace layout
    unsigned short* hwb = (unsigned short*)d_ws;        // 50000*96 bf16 = 9.6 MB
    unsigned short* wt  = hwb + (size_t)M_NODES * NDIM; // 96*256 bf16 = 48 KB
    int* off      = (int*)(wt + KDIM * NDIM);           // 50001 (+3 pad)
    int* bcnt     = off + 50004;                        // 196
    int* bbase    = bcnt + 200;                         // 197 (+pad)
    int* gcursor  = bbase + 200;                        // 196
    unsigned* binned = (unsigned*)(gcursor + 200);      // 800000
    int* edge_src = (int*)(binned + NEDGE);             // 800000

    prep_w_kernel<<<(KDIM * NDIM + 255) / 256, 256, 0, stream>>>(w, wt, bcnt);
    bucket_count_kernel<<<NBLK_SC, 256, 0, stream>>>(dst, bcnt);
    bucket_scan_kernel<<<1, 256, 0, stream>>>(bcnt, bbase, gcursor, off);
    bin_scatter_kernel<<<NBLK_SC, 256, 0, stream>>>(src, dst, gcursor, binned);
    csr_build_kernel<<<NBUCKET, 256, 0, stream>>>(binned, bbase, off, edge_src);

    gemm_mfma_kernel<<<(M_NODES + BM - 1) / BM, 256, 0, stream>>>(h, norm, wt, hwb);

    aggregate_kernel<<<(M_NODES + 15) / 16, 192, 0, stream>>>(hwb, off, edge_src, norm, out);
}

// Round 9
// 75.890 us; speedup vs baseline: 14.4414x; 1.3086x over previous
//
#include <hip/hip_runtime.h>

#define M_NODES 50000
#define KDIM    256
#define NDIM    96
#define NEDGE   800000
#define BM      64     // gemm rows per block
#define NPB     64     // nodes per bucket
#define NBUCK   782    // ceil(50000/64)
#define CAPB    1536   // per-bucket edge capacity (mean 1023, sigma 32 -> +16s)
#define EPB     2048   // edges per bin_scatter block
#define NBLK_SC 391    // ceil(800000/2048)

typedef short bf16x8 __attribute__((ext_vector_type(8)));   // 8 bf16 (4 VGPRs)
typedef float f32x4  __attribute__((ext_vector_type(4)));

// round-to-nearest-even f32 -> bf16 (as u16)
__device__ inline unsigned short f2bf(float x) {
    unsigned u = __float_as_uint(x);
    u = (u + 0x7fffu + ((u >> 16) & 1u)) >> 16;
    return (unsigned short)u;
}
__device__ inline unsigned pack2bf(float x, float y) {
    return (unsigned)f2bf(x) | ((unsigned)f2bf(y) << 16);
}

// -------- Kernel 0: Wt[n][k] = bf16(W[k][n]); block 0 inits cursors ----
__global__ __launch_bounds__(256) void prep_w_kernel(
    const float* __restrict__ w, unsigned short* __restrict__ wt,
    int* __restrict__ gcursor)
{
    if (blockIdx.x == 0)
        for (int i = threadIdx.x; i < NBUCK; i += 256)
            gcursor[i] = i * CAPB;
    int i = blockIdx.x * 256 + threadIdx.x;   // over 96*256
    if (i < KDIM * NDIM) {
        int n = i >> 8;        // 0..95
        int k = i & 255;       // 0..255
        wt[i] = f2bf(w[(size_t)k * NDIM + n]);
    }
}

// -------- Kernel 1: hwb = bf16((h @ W) * norm) via MFMA ----------------
// A (h rows) global->reg with inline f32->bf16 cvt; W in swizzled LDS.
__global__ __launch_bounds__(256) void gemm_mfma_kernel(
    const float* __restrict__ h, const float* __restrict__ norm,
    const unsigned short* __restrict__ wt, unsigned short* __restrict__ hwb)
{
    __shared__ unsigned short w_lds[96 * 256];   // 96 rows x 512B = 48 KB

    const int tid  = threadIdx.x;
    const int lane = tid & 63;
    const int wv   = tid >> 6;                   // 0..3
    const int row0 = blockIdx.x * BM;

    // stage Wt -> w_lds (swizzled), 12 x 16B per thread
#pragma unroll
    for (int it = 0; it < 12; ++it) {
        int idx = tid + it * 256;                // 0..3071
        int n   = idx >> 5;                      // 0..95
        int kb  = (idx & 31) * 16;               // byte in row
        uint4 v = *reinterpret_cast<const uint4*>(
            reinterpret_cast<const char*>(wt) + n * 512 + kb);
        *reinterpret_cast<uint4*>(
            reinterpret_cast<char*>(w_lds) + n * 512 + (kb ^ ((n & 7) << 4))) = v;
    }
    __syncthreads();

    f32x4 acc[6];
#pragma unroll
    for (int f = 0; f < 6; ++f) acc[f] = (f32x4){0.f, 0.f, 0.f, 0.f};

    const int ar  = wv * 16 + (lane & 15);       // A row within tile
    const int kg  = lane >> 4;                   // 0..3 (8-elem k-group)
    int arow = row0 + ar;
    if (arow >= M_NODES) arow = M_NODES - 1;     // clamp; results discarded
    const float* __restrict__ hrow = h + (size_t)arow * KDIM;

#pragma unroll
    for (int s = 0; s < 8; ++s) {
        const int k0 = s * 32 + kg * 8;
        float4 p = *reinterpret_cast<const float4*>(hrow + k0);
        float4 q = *reinterpret_cast<const float4*>(hrow + k0 + 4);
        union { bf16x8 v; unsigned u[4]; } a;
        a.u[0] = pack2bf(p.x, p.y);
        a.u[1] = pack2bf(p.z, p.w);
        a.u[2] = pack2bf(q.x, q.y);
        a.u[3] = pack2bf(q.z, q.w);

        const int kb = s * 64 + kg * 16;         // byte offset of k-slice
#pragma unroll
        for (int f = 0; f < 6; ++f) {
            int n = f * 16 + (lane & 15);
            bf16x8 b = *reinterpret_cast<const bf16x8*>(
                reinterpret_cast<const char*>(w_lds) + n * 512 + (kb ^ ((n & 7) << 4)));
            acc[f] = __builtin_amdgcn_mfma_f32_16x16x32_bf16(a.v, b, acc[f], 0, 0, 0);
        }
    }

    // epilogue: C/D layout col=lane&15, row=(lane>>4)*4+reg
    const int crow = wv * 16 + (lane >> 4) * 4;
    const int ccol = lane & 15;
#pragma unroll
    for (int r = 0; r < 4; ++r) {
        int row = row0 + crow + r;
        if (row < M_NODES) {
            float nv = norm[row];
#pragma unroll
            for (int f = 0; f < 6; ++f)
                hwb[(size_t)row * NDIM + f * 16 + ccol] = f2bf(acc[f][r] * nv);
        }
    }
}

// -------- Kernel 2: bin edges into padded per-bucket regions -----------
// bucket = dst>>6. Each block LDS-counts its 2048 edges per bucket,
// reserves contiguous chunks (1 global atomic per touched bucket), writes
// packed (dst&63)<<16 | src. Fixed CAPB padding removes count+scan passes.
__global__ __launch_bounds__(256) void bin_scatter_kernel(
    const int* __restrict__ src, const int* __restrict__ dst,
    int* __restrict__ gcursor, unsigned* __restrict__ binned)
{
    __shared__ int cnt[NBUCK];
    __shared__ int base[NBUCK];
    const int t  = threadIdx.x;
    const int e0 = blockIdx.x * EPB;
    const int e1 = (e0 + EPB < NEDGE) ? e0 + EPB : NEDGE;

    for (int i = t; i < NBUCK; i += 256) cnt[i] = 0;
    __syncthreads();
    for (int e = e0 + t; e < e1; e += 256)
        atomicAdd(&cnt[dst[e] >> 6], 1);
    __syncthreads();
    for (int i = t; i < NBUCK; i += 256) {
        int c = cnt[i];
        base[i] = c ? atomicAdd(&gcursor[i], c) : 0;
    }
    __syncthreads();
    for (int i = t; i < NBUCK; i += 256) cnt[i] = 0;  // reuse as cursor
    __syncthreads();
    for (int e = e0 + t; e < e1; e += 256) {
        int d = dst[e];
        int b = d >> 6;
        int pos = base[b] + atomicAdd(&cnt[b], 1);
        if (pos < (b + 1) * CAPB)                      // overflow guard (never fires)
            binned[pos] = ((unsigned)(d & 63) << 16) | (unsigned)src[e];
    }
}

// -------- Kernel 3: fused per-bucket CSR build + segment sum + relu ----
// One block per bucket: edges -> LDS, per-node histogram + scan + ordered
// placement in LDS, then 12-lanes-per-node gather-aggregate from hwb.
#define ACC8(v)                                        \
    acc[0] += __uint_as_float((v).x << 16);            \
    acc[1] += __uint_as_float((v).x & 0xffff0000u);    \
    acc[2] += __uint_as_float((v).y << 16);            \
    acc[3] += __uint_as_float((v).y & 0xffff0000u);    \
    acc[4] += __uint_as_float((v).z << 16);            \
    acc[5] += __uint_as_float((v).z & 0xffff0000u);    \
    acc[6] += __uint_as_float((v).w << 16);            \
    acc[7] += __uint_as_float((v).w & 0xffff0000u);

__global__ __launch_bounds__(256) void csr_agg_kernel(
    const unsigned* __restrict__ binned, const int* __restrict__ gcursor,
    const unsigned short* __restrict__ hwb, const float* __restrict__ norm,
    float* __restrict__ out)
{
    __shared__ unsigned eL[CAPB];          // raw packed edges (6 KB)
    __shared__ unsigned short oL[CAPB];    // node-ordered src ids (3 KB)
    __shared__ int cnt[NPB];               // histogram / cursor / end
    __shared__ int pfxE[NPB];              // exclusive start

    const int b  = blockIdx.x;
    const int t  = threadIdx.x;
    const int e0 = b * CAPB;
    int cntE = gcursor[b] - e0;
    if (cntE > CAPB) cntE = CAPB;

    for (int i = t; i < cntE; i += 256) eL[i] = binned[e0 + i];
    if (t < NPB) cnt[t] = 0;
    __syncthreads();
    for (int i = t; i < cntE; i += 256)
        atomicAdd(&cnt[(eL[i] >> 16) & 63], 1);
    __syncthreads();
    if (t < NPB) pfxE[t] = cnt[t];
    __syncthreads();
    for (int st = 1; st < NPB; st <<= 1) {
        int o = (t >= st && t < NPB) ? pfxE[t - st] : 0;
        __syncthreads();
        if (t < NPB) pfxE[t] += o;
        __syncthreads();
    }
    if (t < NPB) {                         // inclusive -> exclusive; cursor
        int ex = pfxE[t] - cnt[t];
        pfxE[t] = ex;
        cnt[t]  = ex;
    }
    __syncthreads();
    for (int i = t; i < cntE; i += 256) {
        unsigned v = eL[i];
        int d = (v >> 16) & 63;
        int p = atomicAdd(&cnt[d], 1);
        oL[p] = (unsigned short)(v & 0xffffu);
    }
    __syncthreads();
    // cnt[node] now == segment end; pfxE[node] == segment start.

    // aggregate: 64 nodes x 12 channel-groups = 768 units, 3 passes
#pragma unroll
    for (int pass = 0; pass < 3; ++pass) {
        const int u     = pass * 256 + t;
        const int node  = u / 12;
        const int c8    = u - node * 12;       // channels c8*8 .. +7
        const int gnode = b * NPB + node;
        if (gnode < M_NODES) {
            const int s0 = pfxE[node];
            const int s1 = cnt[node];
            float acc[8] = {0.f, 0.f, 0.f, 0.f, 0.f, 0.f, 0.f, 0.f};
            int e = s0;
            for (; e + 2 <= s1; e += 2) {
                int a0 = oL[e], a1 = oL[e + 1];
                uint4 v0 = *reinterpret_cast<const uint4*>(hwb + (size_t)a0 * NDIM + c8 * 8);
                uint4 v1 = *reinterpret_cast<const uint4*>(hwb + (size_t)a1 * NDIM + c8 * 8);
                ACC8(v0); ACC8(v1);
            }
            if (e < s1) {
                int a0 = oL[e];
                uint4 v0 = *reinterpret_cast<const uint4*>(hwb + (size_t)a0 * NDIM + c8 * 8);
                ACC8(v0);
            }
            const float nv = norm[gnode];
            float4 o0, o1;
            o0.x = fmaxf(acc[0] * nv, 0.f); o0.y = fmaxf(acc[1] * nv, 0.f);
            o0.z = fmaxf(acc[2] * nv, 0.f); o0.w = fmaxf(acc[3] * nv, 0.f);
            o1.x = fmaxf(acc[4] * nv, 0.f); o1.y = fmaxf(acc[5] * nv, 0.f);
            o1.z = fmaxf(acc[6] * nv, 0.f); o1.w = fmaxf(acc[7] * nv, 0.f);
            float4* po = reinterpret_cast<float4*>(out + (size_t)gnode * NDIM + c8 * 8);
            po[0] = o0; po[1] = o1;
        }
    }
}

extern "C" void kernel_launch(void* const* d_in, const int* in_sizes, int n_in,
                              void* d_out, int out_size, void* d_ws, size_t ws_size,
                              hipStream_t stream)
{
    const float* h    = (const float*)d_in[0];
    const float* norm = (const float*)d_in[1];
    const float* w    = (const float*)d_in[2];
    const int*   src  = (const int*)d_in[3];
    const int*   dst  = (const int*)d_in[4];
    float* out = (float*)d_out;

    // workspace layout
    unsigned short* hwb = (unsigned short*)d_ws;        // 50000*96 bf16 = 9.6 MB
    unsigned short* wt  = hwb + (size_t)M_NODES * NDIM; // 96*256 bf16 = 48 KB
    int* gcursor = (int*)(wt + KDIM * NDIM);            // 782 (+pad)
    unsigned* binned = (unsigned*)(gcursor + 800);      // 782*1536 = 4.8 MB

    prep_w_kernel<<<(KDIM * NDIM + 255) / 256, 256, 0, stream>>>(w, wt, gcursor);
    bin_scatter_kernel<<<NBLK_SC, 256, 0, stream>>>(src, dst, gcursor, binned);
    gemm_mfma_kernel<<<(M_NODES + BM - 1) / BM, 256, 0, stream>>>(h, norm, wt, hwb);
    csr_agg_kernel<<<NBUCK, 256, 0, stream>>>(binned, gcursor, hwb, norm, out);
}

// Round 10
// 70.355 us; speedup vs baseline: 15.5776x; 1.0787x over previous
//
#include <hip/hip_runtime.h>

#define M_NODES 50000
#define KDIM    256
#define NDIM    96
#define NEDGE   800000
#define BM      128    // gemm rows per block
#define GEMM_BLKS 391  // ceil(50000/128)
#define NPB     64     // nodes per bucket
#define NBUCK   782    // ceil(50000/64)
#define CAPB    1536   // per-bucket edge capacity (mean 1023, sigma 32 -> +16s)
#define EPB     2048   // edges per scatter block
#define NBLK_SC 391    // ceil(800000/2048)

typedef short bf16x8 __attribute__((ext_vector_type(8)));   // 8 bf16 (4 VGPRs)
typedef float f32x4  __attribute__((ext_vector_type(4)));

// round-to-nearest-even f32 -> bf16 (as u16)
__device__ inline unsigned short f2bf(float x) {
    unsigned u = __float_as_uint(x);
    u = (u + 0x7fffu + ((u >> 16) & 1u)) >> 16;
    return (unsigned short)u;
}
__device__ inline unsigned pack2bf(float x, float y) {
    return (unsigned)f2bf(x) | ((unsigned)f2bf(y) << 16);
}

// -------- Kernel 0: Wt[n][k] = bf16(W[k][n]); block 0 inits cursors ----
__global__ __launch_bounds__(256) void prep_w_kernel(
    const float* __restrict__ w, unsigned short* __restrict__ wt,
    int* __restrict__ gcursor)
{
    if (blockIdx.x == 0)
        for (int i = threadIdx.x; i < NBUCK; i += 256)
            gcursor[i] = i * CAPB;
    int i = blockIdx.x * 256 + threadIdx.x;   // over 96*256
    if (i < KDIM * NDIM) {
        int n = i >> 8;        // 0..95
        int k = i & 255;       // 0..255
        wt[i] = f2bf(w[(size_t)k * NDIM + n]);
    }
}

// -------- Kernel 1 (fat): gemm blocks [0,391) + scatter blocks [391,782)
// GEMM: BM=128 rows/block via MFMA; A global->reg w/ inline bf16 cvt;
//       W in swizzled LDS (48KB), each wave owns 2 row-fragments.
// SCATTER: bucket=dst>>6; LDS count -> chunk reserve -> packed write into
//       fixed-capacity (CAPB) per-bucket regions.
__global__ __launch_bounds__(256) void fused_gemm_scatter_kernel(
    const float* __restrict__ h, const float* __restrict__ norm,
    const unsigned short* __restrict__ wt, unsigned short* __restrict__ hwb,
    const int* __restrict__ src, const int* __restrict__ dst,
    int* __restrict__ gcursor, unsigned* __restrict__ binned)
{
    __shared__ __align__(16) char smem[96 * 512];   // 48 KB, union'd

    const int tid = threadIdx.x;

    if (blockIdx.x < GEMM_BLKS) {
        // ---------------- GEMM path ----------------
        unsigned short* w_lds = reinterpret_cast<unsigned short*>(smem);
        const int lane = tid & 63;
        const int wv   = tid >> 6;                   // 0..3
        const int row0 = blockIdx.x * BM;

        // stage Wt -> w_lds (swizzled), 12 x 16B per thread
#pragma unroll
        for (int it = 0; it < 12; ++it) {
            int idx = tid + it * 256;                // 0..3071
            int n   = idx >> 5;                      // 0..95
            int kb  = (idx & 31) * 16;               // byte in row
            uint4 v = *reinterpret_cast<const uint4*>(
                reinterpret_cast<const char*>(wt) + n * 512 + kb);
            *reinterpret_cast<uint4*>(
                reinterpret_cast<char*>(w_lds) + n * 512 + (kb ^ ((n & 7) << 4))) = v;
        }
        __syncthreads();

        f32x4 acc0[6], acc1[6];
#pragma unroll
        for (int f = 0; f < 6; ++f) {
            acc0[f] = (f32x4){0.f, 0.f, 0.f, 0.f};
            acc1[f] = (f32x4){0.f, 0.f, 0.f, 0.f};
        }

        const int ar = wv * 16 + (lane & 15);        // A row within tile
        const int kg = lane >> 4;                    // 0..3 (8-elem k-group)
        int arow0 = row0 + ar;
        int arow1 = row0 + ar + 64;
        if (arow0 >= M_NODES) arow0 = M_NODES - 1;   // clamp; results discarded
        if (arow1 >= M_NODES) arow1 = M_NODES - 1;
        const float* __restrict__ hr0 = h + (size_t)arow0 * KDIM;
        const float* __restrict__ hr1 = h + (size_t)arow1 * KDIM;

#pragma unroll
        for (int s = 0; s < 8; ++s) {
            const int k0 = s * 32 + kg * 8;
            float4 p0 = *reinterpret_cast<const float4*>(hr0 + k0);
            float4 q0 = *reinterpret_cast<const float4*>(hr0 + k0 + 4);
            float4 p1 = *reinterpret_cast<const float4*>(hr1 + k0);
            float4 q1 = *reinterpret_cast<const float4*>(hr1 + k0 + 4);
            union { bf16x8 v; unsigned u[4]; } a0, a1;
            a0.u[0] = pack2bf(p0.x, p0.y); a0.u[1] = pack2bf(p0.z, p0.w);
            a0.u[2] = pack2bf(q0.x, q0.y); a0.u[3] = pack2bf(q0.z, q0.w);
            a1.u[0] = pack2bf(p1.x, p1.y); a1.u[1] = pack2bf(p1.z, p1.w);
            a1.u[2] = pack2bf(q1.x, q1.y); a1.u[3] = pack2bf(q1.z, q1.w);

            const int kb = s * 64 + kg * 16;         // byte offset of k-slice
#pragma unroll
            for (int f = 0; f < 6; ++f) {
                int n = f * 16 + (lane & 15);
                bf16x8 b = *reinterpret_cast<const bf16x8*>(
                    reinterpret_cast<const char*>(w_lds) + n * 512 + (kb ^ ((n & 7) << 4)));
                acc0[f] = __builtin_amdgcn_mfma_f32_16x16x32_bf16(a0.v, b, acc0[f], 0, 0, 0);
                acc1[f] = __builtin_amdgcn_mfma_f32_16x16x32_bf16(a1.v, b, acc1[f], 0, 0, 0);
            }
        }

        // epilogue: C/D layout col=lane&15, row=(lane>>4)*4+reg
        const int crow = wv * 16 + (lane >> 4) * 4;
        const int ccol = lane & 15;
#pragma unroll
        for (int r = 0; r < 4; ++r) {
            int rowA = row0 + crow + r;
            if (rowA < M_NODES) {
                float nv = norm[rowA];
#pragma unroll
                for (int f = 0; f < 6; ++f)
                    hwb[(size_t)rowA * NDIM + f * 16 + ccol] = f2bf(acc0[f][r] * nv);
            }
            int rowB = rowA + 64;
            if (rowB < M_NODES) {
                float nv = norm[rowB];
#pragma unroll
                for (int f = 0; f < 6; ++f)
                    hwb[(size_t)rowB * NDIM + f * 16 + ccol] = f2bf(acc1[f][r] * nv);
            }
        }
    } else {
        // ---------------- SCATTER path ----------------
        int* cnt  = reinterpret_cast<int*>(smem);
        int* base = cnt + NBUCK;
        const int blk = blockIdx.x - GEMM_BLKS;
        const int e0 = blk * EPB;
        const int e1 = (e0 + EPB < NEDGE) ? e0 + EPB : NEDGE;

        for (int i = tid; i < NBUCK; i += 256) cnt[i] = 0;
        __syncthreads();
        for (int e = e0 + tid; e < e1; e += 256)
            atomicAdd(&cnt[dst[e] >> 6], 1);
        __syncthreads();
        for (int i = tid; i < NBUCK; i += 256) {
            int c = cnt[i];
            base[i] = c ? atomicAdd(&gcursor[i], c) : 0;
        }
        __syncthreads();
        for (int i = tid; i < NBUCK; i += 256) cnt[i] = 0;  // reuse as cursor
        __syncthreads();
        for (int e = e0 + tid; e < e1; e += 256) {
            int d = dst[e];
            int b = d >> 6;
            int pos = base[b] + atomicAdd(&cnt[b], 1);
            if (pos < (b + 1) * CAPB)                        // overflow guard
                binned[pos] = ((unsigned)(d & 63) << 16) | (unsigned)src[e];
        }
    }
}

// -------- Kernel 2: fused per-bucket CSR build + segment sum + relu ----
#define ACCV(A, v)                                     \
    A[0] += __uint_as_float((v).x << 16);              \
    A[1] += __uint_as_float((v).x & 0xffff0000u);      \
    A[2] += __uint_as_float((v).y << 16);              \
    A[3] += __uint_as_float((v).y & 0xffff0000u);      \
    A[4] += __uint_as_float((v).z << 16);              \
    A[5] += __uint_as_float((v).z & 0xffff0000u);      \
    A[6] += __uint_as_float((v).w << 16);              \
    A[7] += __uint_as_float((v).w & 0xffff0000u);

__global__ __launch_bounds__(256) void csr_agg_kernel(
    const unsigned* __restrict__ binned, const int* __restrict__ gcursor,
    const unsigned short* __restrict__ hwb, const float* __restrict__ norm,
    float* __restrict__ out)
{
    __shared__ unsigned eL[CAPB];          // raw packed edges (6 KB)
    __shared__ unsigned short oL[CAPB];    // node-ordered src ids (3 KB)
    __shared__ int cnt[NPB];               // histogram / cursor / end
    __shared__ int pfxE[NPB];              // exclusive start

    const int b  = blockIdx.x;
    const int t  = threadIdx.x;
    const int e0 = b * CAPB;
    int cntE = gcursor[b] - e0;
    if (cntE > CAPB) cntE = CAPB;

    for (int i = t; i < cntE; i += 256) eL[i] = binned[e0 + i];
    if (t < NPB) cnt[t] = 0;
    __syncthreads();
    for (int i = t; i < cntE; i += 256)
        atomicAdd(&cnt[(eL[i] >> 16) & 63], 1);
    __syncthreads();
    if (t < NPB) pfxE[t] = cnt[t];
    __syncthreads();
    for (int st = 1; st < NPB; st <<= 1) {
        int o = (t >= st && t < NPB) ? pfxE[t - st] : 0;
        __syncthreads();
        if (t < NPB) pfxE[t] += o;
        __syncthreads();
    }
    if (t < NPB) {                         // inclusive -> exclusive; cursor
        int ex = pfxE[t] - cnt[t];
        pfxE[t] = ex;
        cnt[t]  = ex;
    }
    __syncthreads();
    for (int i = t; i < cntE; i += 256) {
        unsigned v = eL[i];
        int d = (v >> 16) & 63;
        int p = atomicAdd(&cnt[d], 1);
        oL[p] = (unsigned short)(v & 0xffffu);
    }
    __syncthreads();
    // cnt[node] == segment end; pfxE[node] == segment start.

    // aggregate: 64 nodes x 12 channel-groups = 768 units, 3 passes
#pragma unroll
    for (int pass = 0; pass < 3; ++pass) {
        const int u     = pass * 256 + t;
        const int node  = u / 12;
        const int c8    = u - node * 12;       // channels c8*8 .. +7
        const int gnode = b * NPB + node;
        if (gnode < M_NODES) {
            const int s0 = pfxE[node];
            const int s1 = cnt[node];
            float acc[8]  = {0.f, 0.f, 0.f, 0.f, 0.f, 0.f, 0.f, 0.f};
            float acc2[8] = {0.f, 0.f, 0.f, 0.f, 0.f, 0.f, 0.f, 0.f};
            int e = s0;
            for (; e + 4 <= s1; e += 4) {
                int a0 = oL[e], a1 = oL[e + 1], a2 = oL[e + 2], a3 = oL[e + 3];
                uint4 v0 = *reinterpret_cast<const uint4*>(hwb + (size_t)a0 * NDIM + c8 * 8);
                uint4 v1 = *reinterpret_cast<const uint4*>(hwb + (size_t)a1 * NDIM + c8 * 8);
                uint4 v2 = *reinterpret_cast<const uint4*>(hwb + (size_t)a2 * NDIM + c8 * 8);
                uint4 v3 = *reinterpret_cast<const uint4*>(hwb + (size_t)a3 * NDIM + c8 * 8);
                ACCV(acc, v0); ACCV(acc2, v1); ACCV(acc, v2); ACCV(acc2, v3);
            }
            for (; e < s1; ++e) {
                int a0 = oL[e];
                uint4 v0 = *reinterpret_cast<const uint4*>(hwb + (size_t)a0 * NDIM + c8 * 8);
                ACCV(acc, v0);
            }
            const float nv = norm[gnode];
            float4 o0, o1;
            o0.x = fmaxf((acc[0] + acc2[0]) * nv, 0.f);
            o0.y = fmaxf((acc[1] + acc2[1]) * nv, 0.f);
            o0.z = fmaxf((acc[2] + acc2[2]) * nv, 0.f);
            o0.w = fmaxf((acc[3] + acc2[3]) * nv, 0.f);
            o1.x = fmaxf((acc[4] + acc2[4]) * nv, 0.f);
            o1.y = fmaxf((acc[5] + acc2[5]) * nv, 0.f);
            o1.z = fmaxf((acc[6] + acc2[6]) * nv, 0.f);
            o1.w = fmaxf((acc[7] + acc2[7]) * nv, 0.f);
            float4* po = reinterpret_cast<float4*>(out + (size_t)gnode * NDIM + c8 * 8);
            po[0] = o0; po[1] = o1;
        }
    }
}

extern "C" void kernel_launch(void* const* d_in, const int* in_sizes, int n_in,
                              void* d_out, int out_size, void* d_ws, size_t ws_size,
                              hipStream_t stream)
{
    const float* h    = (const float*)d_in[0];
    const float* norm = (const float*)d_in[1];
    const float* w    = (const float*)d_in[2];
    const int*   src  = (const int*)d_in[3];
    const int*   dst  = (const int*)d_in[4];
    float* out = (float*)d_out;

    // workspace layout
    unsigned short* hwb = (unsigned short*)d_ws;        // 50000*96 bf16 = 9.6 MB
    unsigned short* wt  = hwb + (size_t)M_NODES * NDIM; // 96*256 bf16 = 48 KB
    int* gcursor = (int*)(wt + KDIM * NDIM);            // 782 (+pad)
    unsigned* binned = (unsigned*)(gcursor + 800);      // 782*1536 = 4.8 MB

    prep_w_kernel<<<(KDIM * NDIM + 255) / 256, 256, 0, stream>>>(w, wt, gcursor);
    fused_gemm_scatter_kernel<<<GEMM_BLKS + NBLK_SC, 256, 0, stream>>>(
        h, norm, wt, hwb, src, dst, gcursor, binned);
    csr_agg_kernel<<<NBUCK, 256, 0, stream>>>(binned, gcursor, hwb, norm, out);
}